// Round 3
// baseline (2142.714 us; speedup 1.0000x reference)
//
#include <hip/hip_runtime.h>
#include <math.h>

#define NN 100000
#define NE 1600000
#define NF 128
#define NOUT 3
#define NEGS 0.02f
#define GEPS 1e-5f

typedef __attribute__((ext_vector_type(8))) short bf16x8;
typedef __attribute__((ext_vector_type(4))) float f32x4;

__device__ __forceinline__ unsigned short bf16_rn(float f) {
    unsigned u = __float_as_uint(f);
    unsigned r = u + 0x7FFFu + ((u >> 16) & 1u);
    return (unsigned short)(r >> 16);
}
__device__ __forceinline__ float bf16_tf(unsigned short h) {
    return __uint_as_float((unsigned)h << 16);
}

// ---------------- CSR build ----------------
__global__ void k_hist(const int* __restrict__ dst, int* __restrict__ counts) {
    int i = blockIdx.x * blockDim.x + threadIdx.x;
    if (i < NE) atomicAdd(&counts[dst[i]], 1);
}

__global__ void k_scan1(const int* __restrict__ counts, int* __restrict__ bsums) {
    __shared__ int s[256];
    int i = blockIdx.x * 256 + threadIdx.x;
    s[threadIdx.x] = (i < NN) ? counts[i] : 0;
    __syncthreads();
    for (int off = 128; off > 0; off >>= 1) {
        if (threadIdx.x < off) s[threadIdx.x] += s[threadIdx.x + off];
        __syncthreads();
    }
    if (threadIdx.x == 0) bsums[blockIdx.x] = s[0];
}

__global__ void k_scan2(int* __restrict__ bsums, int nb) {
    __shared__ int s[512];
    int t = threadIdx.x;
    int v = (t < nb) ? bsums[t] : 0;
    s[t] = v;
    __syncthreads();
    for (int off = 1; off < 512; off <<= 1) {
        int u = (t >= off) ? s[t - off] : 0;
        __syncthreads();
        s[t] += u;
        __syncthreads();
    }
    if (t < nb) bsums[t] = s[t] - v;   // exclusive
}

__global__ void k_scan3(const int* __restrict__ counts, const int* __restrict__ bsums,
                        int* __restrict__ offsets, int* __restrict__ cursor) {
    __shared__ int s[256];
    int i = blockIdx.x * 256 + threadIdx.x;
    int v = (i < NN) ? counts[i] : 0;
    s[threadIdx.x] = v;
    __syncthreads();
    for (int off = 1; off < 256; off <<= 1) {
        int u = (threadIdx.x >= off) ? s[threadIdx.x - off] : 0;
        __syncthreads();
        s[threadIdx.x] += u;
        __syncthreads();
    }
    int excl = s[threadIdx.x] - v + bsums[blockIdx.x];
    if (i < NN) { offsets[i] = excl; cursor[i] = excl; }
    else if (i == NN) { offsets[i] = excl; }
}

__global__ void k_scatter(const int* __restrict__ src, const int* __restrict__ dst,
                          int* __restrict__ cursor, int* __restrict__ csr) {
    int i = blockIdx.x * blockDim.x + threadIdx.x;
    if (i < NE) {
        int d = dst[i];
        int p = atomicAdd(&cursor[d], 1);
        csr[p] = src[i];
    }
}

// ---------------- weight split: Wcat[L][o][k] -> bf16 hi/lo ----------------
__global__ void k_wsplit(const float* __restrict__ Wl, const float* __restrict__ Wr,
                         unsigned short* __restrict__ whi, unsigned short* __restrict__ wlo) {
    int i = blockIdx.x * 256 + threadIdx.x;
    if (i >= 6 * NF * 256) return;
    int L = i >> 15;           // /32768
    int rem = i & 32767;
    int o = rem >> 8;
    int k = rem & 255;
    float v = (k < NF) ? Wl[L * NF * NF + o * NF + k] : Wr[L * NF * NF + o * NF + (k - NF)];
    unsigned short h = bf16_rn(v);
    whi[i] = h;
    wlo[i] = bf16_rn(v - bf16_tf(h));
}

// ---------------- x split (layer-0 h operand) ----------------
__global__ void k_xsplit(const float* __restrict__ x,
                         unsigned short* __restrict__ hhi, unsigned short* __restrict__ hlo) {
    int i = blockIdx.x * 256 + threadIdx.x;   // over NN*NF/4 float4s
    float4 v = ((const float4*)x)[i];
    ushort4 h, l;
    h.x = bf16_rn(v.x); l.x = bf16_rn(v.x - bf16_tf(h.x));
    h.y = bf16_rn(v.y); l.y = bf16_rn(v.y - bf16_tf(h.y));
    h.z = bf16_rn(v.z); l.z = bf16_rn(v.z - bf16_tf(h.z));
    h.w = bf16_rn(v.w); l.w = bf16_rn(v.w - bf16_tf(h.w));
    ((ushort4*)hhi)[i] = h;
    ((ushort4*)hlo)[i] = l;
}

// ---------------- max aggregation (CSR), emits bf16 hi/lo split ----------------
__global__ __launch_bounds__(256) void k_aggmax(const float* __restrict__ h,
                                                const int* __restrict__ offsets,
                                                const int* __restrict__ csr,
                                                unsigned short* __restrict__ mhi,
                                                unsigned short* __restrict__ mlo) {
    int node = blockIdx.x * 2 + (threadIdx.x >> 7);
    int f = threadIdx.x & 127;
    if (node >= NN) return;
    int beg = offsets[node], end = offsets[node + 1];
    float acc = -INFINITY;
    int e = beg;
    for (; e + 4 <= end; e += 4) {
        int s0 = csr[e], s1 = csr[e + 1], s2 = csr[e + 2], s3 = csr[e + 3];
        float v0 = h[s0 * NF + f], v1 = h[s1 * NF + f];
        float v2 = h[s2 * NF + f], v3 = h[s3 * NF + f];
        acc = fmaxf(acc, fmaxf(fmaxf(v0, v1), fmaxf(v2, v3)));
    }
    for (; e < end; ++e) acc = fmaxf(acc, h[csr[e] * NF + f]);
    float val = (beg == end) ? 0.0f : acc;
    unsigned short hi = bf16_rn(val);
    mhi[node * NF + f] = hi;
    mlo[node * NF + f] = bf16_rn(val - bf16_tf(hi));
}

// ---------------- MFMA GEMM: Z = [m|h] @ Wcat.T + b, split-bf16 3-product ----------------
// Block: 256 thr = 4 waves; wave w handles nodes n0+w*16 .. +15, all 128 outs.
__global__ __launch_bounds__(256) void k_gemm(const unsigned short* __restrict__ mhi,
                                              const unsigned short* __restrict__ mlo,
                                              const unsigned short* __restrict__ hhi,
                                              const unsigned short* __restrict__ hlo,
                                              const unsigned short* __restrict__ whi,
                                              const unsigned short* __restrict__ wlo,
                                              const float* __restrict__ bias,
                                              float* __restrict__ Z,
                                              float* __restrict__ stats) {
    int tid = threadIdx.x;
    int w = tid >> 6;
    int l = tid & 63;
    int n0 = blockIdx.x * 64 + w * 16;
    int arow = l & 15;
    int kg = l >> 4;              // 0..3
    int koff = kg * 8;

    int an = n0 + arow;
    if (an >= NN) an = NN - 1;    // clamp for loads only

    f32x4 acc[8];
#pragma unroll
    for (int nt = 0; nt < 8; nt++) acc[nt] = (f32x4){0.f, 0.f, 0.f, 0.f};

    __shared__ float red[2][NF];
    if (tid < NF) { red[0][tid] = 0.f; red[1][tid] = 0.f; }

#pragma unroll
    for (int ks = 0; ks < 8; ks++) {
        int k0 = ks * 32;
        const unsigned short* Ahi = (k0 < NF) ? mhi : hhi;
        const unsigned short* Alo = (k0 < NF) ? mlo : hlo;
        int ak = (k0 < NF) ? k0 : (k0 - NF);
        bf16x8 a_hi = *(const bf16x8*)&Ahi[(size_t)an * NF + ak + koff];
        bf16x8 a_lo = *(const bf16x8*)&Alo[(size_t)an * NF + ak + koff];

        bf16x8 b_hi[8], b_lo[8];
#pragma unroll
        for (int nt = 0; nt < 8; nt++) {
            size_t widx = (size_t)(nt * 16 + arow) * 256 + k0 + koff;
            b_hi[nt] = *(const bf16x8*)&whi[widx];
            b_lo[nt] = *(const bf16x8*)&wlo[widx];
        }
#pragma unroll
        for (int nt = 0; nt < 8; nt++)
            acc[nt] = __builtin_amdgcn_mfma_f32_16x16x32_bf16(a_hi, b_hi[nt], acc[nt], 0, 0, 0);
#pragma unroll
        for (int nt = 0; nt < 8; nt++)
            acc[nt] = __builtin_amdgcn_mfma_f32_16x16x32_bf16(a_hi, b_lo[nt], acc[nt], 0, 0, 0);
#pragma unroll
        for (int nt = 0; nt < 8; nt++)
            acc[nt] = __builtin_amdgcn_mfma_f32_16x16x32_bf16(a_lo, b_hi[nt], acc[nt], 0, 0, 0);
    }

    __syncthreads();   // red[] zero-init visible

    // epilogue: D layout col=l&15 (feature-in-tile), row=(l>>4)*4+reg (node-in-tile)
#pragma unroll
    for (int nt = 0; nt < 8; nt++) {
        int f = nt * 16 + (l & 15);
        float b = bias[f];
        float s = 0.f, q = 0.f;
#pragma unroll
        for (int r = 0; r < 4; r++) {
            int n = n0 + kg * 4 + r;
            float v = acc[nt][r] + b;
            if (n < NN) {
                Z[(size_t)n * NF + f] = v;
                s += v;
                q += v * v;
            }
        }
        s += __shfl_xor(s, 16); s += __shfl_xor(s, 32);
        q += __shfl_xor(q, 16); q += __shfl_xor(q, 32);
        if (l < 16) {
            atomicAdd(&red[0][f], s);
            atomicAdd(&red[1][f], q);
        }
    }
    __syncthreads();
    if (tid < NF) {
        atomicAdd(&stats[tid], red[0][tid]);
        atomicAdd(&stats[NF + tid], red[1][tid]);
    }
}

// ---------------- GraphNorm + LeakyReLU (in-place) + bf16 hi/lo emit ----------------
__global__ __launch_bounds__(256) void k_norm(const float* __restrict__ stats,
                                              const float* __restrict__ gamma,
                                              const float* __restrict__ beta,
                                              const float* __restrict__ alpha,
                                              float* __restrict__ Z,
                                              unsigned short* __restrict__ zhi,
                                              unsigned short* __restrict__ zlo) {
    __shared__ float sc[NF], sh[NF];
    int tid = threadIdx.x;
    if (tid < NF) {
        float mean = stats[tid] * (1.0f / NN);
        float ex2 = stats[NF + tid] * (1.0f / NN);
        float a = alpha[tid];
        float am = a * mean;
        float var = ex2 - 2.f * am * mean + am * am;
        float inv = rsqrtf(var + GEPS);
        float g = gamma[tid] * inv;
        sc[tid] = g;
        sh[tid] = beta[tid] - g * am;
    }
    __syncthreads();
    int i = blockIdx.x * 256 + tid;   // NN*NF/4 threads
    float4 z = ((const float4*)Z)[i];
    int f = (i & 31) * 4;
    float r0 = sc[f + 0] * z.x + sh[f + 0]; r0 = r0 > 0.f ? r0 : NEGS * r0;
    float r1 = sc[f + 1] * z.y + sh[f + 1]; r1 = r1 > 0.f ? r1 : NEGS * r1;
    float r2 = sc[f + 2] * z.z + sh[f + 2]; r2 = r2 > 0.f ? r2 : NEGS * r2;
    float r3 = sc[f + 3] * z.w + sh[f + 3]; r3 = r3 > 0.f ? r3 : NEGS * r3;
    ((float4*)Z)[i] = make_float4(r0, r1, r2, r3);
    ushort4 h, lo;
    h.x = bf16_rn(r0); lo.x = bf16_rn(r0 - bf16_tf(h.x));
    h.y = bf16_rn(r1); lo.y = bf16_rn(r1 - bf16_tf(h.y));
    h.z = bf16_rn(r2); lo.z = bf16_rn(r2 - bf16_tf(h.z));
    h.w = bf16_rn(r3); lo.w = bf16_rn(r3 - bf16_tf(h.w));
    ((ushort4*)zhi)[i] = h;
    ((ushort4*)zlo)[i] = lo;
}

// ---------------- final layer: out = tanh([m|h] @ Wcat_out.T + b)*0.5 ----------------
__global__ __launch_bounds__(256) void k_final(const unsigned short* __restrict__ mhi,
                                               const unsigned short* __restrict__ mlo,
                                               const unsigned short* __restrict__ hhi,
                                               const unsigned short* __restrict__ hlo,
                                               const float* __restrict__ Wlo_,
                                               const float* __restrict__ blo_,
                                               const float* __restrict__ Wro_,
                                               float* __restrict__ out) {
    __shared__ __align__(16) float W[NOUT][256];
    __shared__ float bb[NOUT];
    int tid = threadIdx.x;
    for (int i = tid; i < NOUT * 256; i += 256) {
        int o = i >> 8, k = i & 255;
        W[o][k] = (k < NF) ? Wlo_[o * NF + k] : Wro_[o * NF + (k - NF)];
    }
    if (tid < NOUT) bb[tid] = blo_[tid];
    __syncthreads();

    int node = blockIdx.x * 64 + (tid >> 2);
    int j = tid & 3;
    if (node >= NN) return;
    const unsigned short* shi = (j < 2) ? mhi : hhi;
    const unsigned short* slo = (j < 2) ? mlo : hlo;
    int kbase = (j & 1) * 64;
    const unsigned short* rh = &shi[(size_t)node * NF + kbase];
    const unsigned short* rl = &slo[(size_t)node * NF + kbase];
    float a0 = 0.f, a1 = 0.f, a2 = 0.f;
#pragma unroll
    for (int q = 0; q < 16; q++) {
        ushort4 vh = *(const ushort4*)&rh[q * 4];
        ushort4 vl = *(const ushort4*)&rl[q * 4];
        float v0 = bf16_tf(vh.x) + bf16_tf(vl.x);
        float v1 = bf16_tf(vh.y) + bf16_tf(vl.y);
        float v2 = bf16_tf(vh.z) + bf16_tf(vl.z);
        float v3 = bf16_tf(vh.w) + bf16_tf(vl.w);
        int k = j * 64 + q * 4;
        float4 w0 = *(const float4*)&W[0][k];
        float4 w1 = *(const float4*)&W[1][k];
        float4 w2 = *(const float4*)&W[2][k];
        a0 += v0 * w0.x + v1 * w0.y + v2 * w0.z + v3 * w0.w;
        a1 += v0 * w1.x + v1 * w1.y + v2 * w1.z + v3 * w1.w;
        a2 += v0 * w2.x + v1 * w2.y + v2 * w2.z + v3 * w2.w;
    }
    a0 += __shfl_down(a0, 2, 4); a0 += __shfl_down(a0, 1, 4);
    a1 += __shfl_down(a1, 2, 4); a1 += __shfl_down(a1, 1, 4);
    a2 += __shfl_down(a2, 2, 4); a2 += __shfl_down(a2, 1, 4);
    if (j == 0) {
        out[node * 3 + 0] = tanhf(a0 + bb[0]) * 0.5f;
        out[node * 3 + 1] = tanhf(a1 + bb[1]) * 0.5f;
        out[node * 3 + 2] = tanhf(a2 + bb[2]) * 0.5f;
    }
}

extern "C" void kernel_launch(void* const* d_in, const int* in_sizes, int n_in,
                              void* d_out, int out_size, void* d_ws, size_t ws_size,
                              hipStream_t stream) {
    const float* x     = (const float*)d_in[0];
    const int*   ei    = (const int*)d_in[1];
    const float* Wl    = (const float*)d_in[2];
    const float* bl    = (const float*)d_in[3];
    const float* Wr    = (const float*)d_in[4];
    const float* Wlo   = (const float*)d_in[5];
    const float* blo   = (const float*)d_in[6];
    const float* Wro   = (const float*)d_in[7];
    const float* gamma = (const float*)d_in[8];
    const float* beta  = (const float*)d_in[9];
    const float* alpha = (const float*)d_in[10];
    float* out = (float*)d_out;

    const int* esrc = ei;
    const int* edst = ei + NE;

    char* ws = (char*)d_ws;
    size_t off = 0;
    auto alloc = [&](size_t bytes) -> void* {
        void* p = ws + off;
        off += (bytes + 255) & ~(size_t)255;
        return p;
    };

    const int NB = (NN + 255) / 256;  // 391
    int*   counts  = (int*)alloc(NN * sizeof(int));
    int*   offsets = (int*)alloc((NN + 1) * sizeof(int));
    int*   cursor  = (int*)alloc(NN * sizeof(int));
    int*   bsums   = (int*)alloc(NB * sizeof(int));
    int*   csr     = (int*)alloc(NE * sizeof(int));
    unsigned short* mhi = (unsigned short*)alloc((size_t)NN * NF * 2);
    unsigned short* mlo = (unsigned short*)alloc((size_t)NN * NF * 2);
    unsigned short* hhi = (unsigned short*)alloc((size_t)NN * NF * 2);
    unsigned short* hlo = (unsigned short*)alloc((size_t)NN * NF * 2);
    float* hfp   = (float*)alloc((size_t)NN * NF * sizeof(float));
    unsigned short* whi6 = (unsigned short*)alloc((size_t)6 * NF * 256 * 2);
    unsigned short* wlo6 = (unsigned short*)alloc((size_t)6 * NF * 256 * 2);
    float* stats = (float*)alloc(6 * 2 * NF * sizeof(float));

    hipMemsetAsync(counts, 0, NN * sizeof(int), stream);
    hipMemsetAsync(stats, 0, 6 * 2 * NF * sizeof(float), stream);

    // CSR build
    k_hist<<<(NE + 255) / 256, 256, 0, stream>>>(edst, counts);
    k_scan1<<<NB, 256, 0, stream>>>(counts, bsums);
    k_scan2<<<1, 512, 0, stream>>>(bsums, NB);
    k_scan3<<<NB, 256, 0, stream>>>(counts, bsums, offsets, cursor);
    k_scatter<<<(NE + 255) / 256, 256, 0, stream>>>(esrc, edst, cursor, csr);

    // one-time splits
    k_wsplit<<<(6 * NF * 256 + 255) / 256, 256, 0, stream>>>(Wl, Wr, whi6, wlo6);
    k_xsplit<<<NN * NF / 4 / 256, 256, 0, stream>>>(x, hhi, hlo);

    const int aggGrid  = (NN + 1) / 2;
    const int gemmGrid = (NN + 63) / 64;     // 1563
    const int normGrid = NN * NF / 4 / 256;  // 12500
    const int finGrid  = (NN + 63) / 64;

    const float* hcur = x;
    for (int L = 0; L < 6; ++L) {
        k_aggmax<<<aggGrid, 256, 0, stream>>>(hcur, offsets, csr, mhi, mlo);
        k_gemm<<<gemmGrid, 256, 0, stream>>>(mhi, mlo, hhi, hlo,
                                             whi6 + (size_t)L * NF * 256,
                                             wlo6 + (size_t)L * NF * 256,
                                             bl + (size_t)L * NF,
                                             hfp, stats + (size_t)L * 2 * NF);
        k_norm<<<normGrid, 256, 0, stream>>>(stats + (size_t)L * 2 * NF,
                                             gamma + (size_t)L * NF,
                                             beta + (size_t)L * NF,
                                             alpha + (size_t)L * NF,
                                             hfp, hhi, hlo);
        hcur = hfp;
    }
    // final layer
    k_aggmax<<<aggGrid, 256, 0, stream>>>(hcur, offsets, csr, mhi, mlo);
    k_final<<<finGrid, 256, 0, stream>>>(mhi, mlo, hhi, hlo, Wlo, blo, Wro, out);
}

// Round 5
// 2021.950 us; speedup vs baseline: 1.0597x; 1.0597x over previous
//
#include <hip/hip_runtime.h>
#include <math.h>

#define NN 100000
#define NE 1600000
#define NF 128
#define NOUT 3
#define NEGS 0.02f
#define GEPS 1e-5f

typedef __attribute__((ext_vector_type(8))) short bf16x8;
typedef __attribute__((ext_vector_type(4))) float f32x4;

__device__ __forceinline__ unsigned short bf16_rn(float f) {
    unsigned u = __float_as_uint(f);
    unsigned r = u + 0x7FFFu + ((u >> 16) & 1u);
    return (unsigned short)(r >> 16);
}
__device__ __forceinline__ float bf16_tf(unsigned short h) {
    return __uint_as_float((unsigned)h << 16);
}

// ---------------- CSR build ----------------
__global__ void k_hist(const int* __restrict__ dst, int* __restrict__ counts) {
    int i = blockIdx.x * blockDim.x + threadIdx.x;
    if (i < NE) atomicAdd(&counts[dst[i]], 1);
}

__global__ void k_scan1(const int* __restrict__ counts, int* __restrict__ bsums) {
    __shared__ int s[256];
    int i = blockIdx.x * 256 + threadIdx.x;
    s[threadIdx.x] = (i < NN) ? counts[i] : 0;
    __syncthreads();
    for (int off = 128; off > 0; off >>= 1) {
        if (threadIdx.x < off) s[threadIdx.x] += s[threadIdx.x + off];
        __syncthreads();
    }
    if (threadIdx.x == 0) bsums[blockIdx.x] = s[0];
}

__global__ void k_scan2(int* __restrict__ bsums, int nb) {
    __shared__ int s[512];
    int t = threadIdx.x;
    int v = (t < nb) ? bsums[t] : 0;
    s[t] = v;
    __syncthreads();
    for (int off = 1; off < 512; off <<= 1) {
        int u = (t >= off) ? s[t - off] : 0;
        __syncthreads();
        s[t] += u;
        __syncthreads();
    }
    if (t < nb) bsums[t] = s[t] - v;   // exclusive
}

__global__ void k_scan3(const int* __restrict__ counts, const int* __restrict__ bsums,
                        int* __restrict__ offsets, int* __restrict__ cursor) {
    __shared__ int s[256];
    int i = blockIdx.x * 256 + threadIdx.x;
    int v = (i < NN) ? counts[i] : 0;
    s[threadIdx.x] = v;
    __syncthreads();
    for (int off = 1; off < 256; off <<= 1) {
        int u = (threadIdx.x >= off) ? s[threadIdx.x - off] : 0;
        __syncthreads();
        s[threadIdx.x] += u;
        __syncthreads();
    }
    int excl = s[threadIdx.x] - v + bsums[blockIdx.x];
    if (i < NN) { offsets[i] = excl; cursor[i] = excl; }
    else if (i == NN) { offsets[i] = excl; }
}

__global__ void k_scatter(const int* __restrict__ src, const int* __restrict__ dst,
                          int* __restrict__ cursor, int* __restrict__ csr) {
    int i = blockIdx.x * blockDim.x + threadIdx.x;
    if (i < NE) {
        int d = dst[i];
        int p = atomicAdd(&cursor[d], 1);
        csr[p] = src[i];
    }
}

// ---------------- weight split: Wcat[L][o][k] -> bf16 hi/lo ----------------
__global__ void k_wsplit(const float* __restrict__ Wl, const float* __restrict__ Wr,
                         unsigned short* __restrict__ whi, unsigned short* __restrict__ wlo) {
    int i = blockIdx.x * 256 + threadIdx.x;
    if (i >= 6 * NF * 256) return;
    int L = i >> 15;
    int rem = i & 32767;
    int o = rem >> 8;
    int k = rem & 255;
    float v = (k < NF) ? Wl[L * NF * NF + o * NF + k] : Wr[L * NF * NF + o * NF + (k - NF)];
    unsigned short h = bf16_rn(v);
    whi[i] = h;
    wlo[i] = bf16_rn(v - bf16_tf(h));
}

// ---------------- x split (layer-0 h operand) ----------------
__global__ void k_xsplit(const float* __restrict__ x,
                         unsigned short* __restrict__ hhi, unsigned short* __restrict__ hlo) {
    int i = blockIdx.x * 256 + threadIdx.x;
    float4 v = ((const float4*)x)[i];
    ushort4 h, l;
    h.x = bf16_rn(v.x); l.x = bf16_rn(v.x - bf16_tf(h.x));
    h.y = bf16_rn(v.y); l.y = bf16_rn(v.y - bf16_tf(h.y));
    h.z = bf16_rn(v.z); l.z = bf16_rn(v.z - bf16_tf(h.z));
    h.w = bf16_rn(v.w); l.w = bf16_rn(v.w - bf16_tf(h.w));
    ((ushort4*)hhi)[i] = h;
    ((ushort4*)hlo)[i] = l;
}

// ---------------- max aggregation (CSR), emits bf16 hi/lo split ----------------
__global__ __launch_bounds__(256) void k_aggmax(const float* __restrict__ h,
                                                const int* __restrict__ offsets,
                                                const int* __restrict__ csr,
                                                unsigned short* __restrict__ mhi,
                                                unsigned short* __restrict__ mlo) {
    int node = blockIdx.x * 2 + (threadIdx.x >> 7);
    int f = threadIdx.x & 127;
    if (node >= NN) return;
    int beg = offsets[node], end = offsets[node + 1];
    float acc = -INFINITY;
    int e = beg;
    for (; e + 4 <= end; e += 4) {
        int s0 = csr[e], s1 = csr[e + 1], s2 = csr[e + 2], s3 = csr[e + 3];
        float v0 = h[s0 * NF + f], v1 = h[s1 * NF + f];
        float v2 = h[s2 * NF + f], v3 = h[s3 * NF + f];
        acc = fmaxf(acc, fmaxf(fmaxf(v0, v1), fmaxf(v2, v3)));
    }
    for (; e < end; ++e) acc = fmaxf(acc, h[csr[e] * NF + f]);
    float val = (beg == end) ? 0.0f : acc;
    unsigned short hi = bf16_rn(val);
    mhi[node * NF + f] = hi;
    mlo[node * NF + f] = bf16_rn(val - bf16_tf(hi));
}

// ---------------- MFMA GEMM, weights resident in LDS (lane-linear fragment layout)
// grid (391, 2): x = 256-node tile, y = out-half (64 outs). 512 thr = 8 waves.
// Wave w: nodes tile*256 + w*32 .. +31 (2 groups of 16), 64 outs.
// LDS 64KB: granule (arr,nt,ks,lane) at element arr*16384 + (nt*512+ks*64+lane)*8
// -> every ds_read_b128 is 64 lanes x consecutive 16B = conflict-free.
__global__ __launch_bounds__(512) void k_gemm(const unsigned short* __restrict__ mhi,
                                              const unsigned short* __restrict__ mlo,
                                              const unsigned short* __restrict__ hhi,
                                              const unsigned short* __restrict__ hlo,
                                              const unsigned short* __restrict__ whi,
                                              const unsigned short* __restrict__ wlo,
                                              const float* __restrict__ bias,
                                              float* __restrict__ Z) {
    __shared__ __align__(16) unsigned short wlds[32768];   // 64KB exactly
    const int tid = threadIdx.x;
    const int half = blockIdx.y;
    const int w = tid >> 6;
    const int l = tid & 63;
    const int arow = l & 15;
    const int kg = l >> 4;

    // ---- stage weights into fragment order (tid-linear LDS writes) ----
#pragma unroll
    for (int i = 0; i < 8; i++) {
        int gd = tid + i * 512;            // 0..4095
        int arr = gd >> 11;                // 0=hi, 1=lo
        int rem = gd & 2047;
        int nt = rem >> 9;                 // 0..3
        int ks = (rem >> 6) & 7;           // 0..7
        int ls = rem & 63;                 // lane slot
        int r = nt * 16 + (ls & 15);       // row within half
        int g = ks * 4 + (ls >> 4);        // granule within 256-wide row
        const unsigned short* srcw = arr ? wlo : whi;
        bf16x8 v = *(const bf16x8*)&srcw[(size_t)(half * 64 + r) * 256 + g * 8];
        *(bf16x8*)&wlds[arr * 16384 + rem * 8] = v;
    }
    __syncthreads();

    const int nbase = blockIdx.x * 256 + w * 32;
    int an0 = nbase + arow;      if (an0 > NN - 1) an0 = NN - 1;
    int an1 = nbase + 16 + arow; if (an1 > NN - 1) an1 = NN - 1;

    f32x4 acc0[4], acc1[4];
#pragma unroll
    for (int nt = 0; nt < 4; nt++) {
        acc0[nt] = (f32x4){0.f, 0.f, 0.f, 0.f};
        acc1[nt] = (f32x4){0.f, 0.f, 0.f, 0.f};
    }

#pragma unroll
    for (int ks = 0; ks < 8; ks++) {
        const unsigned short* Ahi = (ks < 4) ? mhi : hhi;
        const unsigned short* Alo = (ks < 4) ? mlo : hlo;
        const int ak = (ks & 3) * 32 + kg * 8;
        bf16x8 a_hi0 = *(const bf16x8*)&Ahi[(size_t)an0 * NF + ak];
        bf16x8 a_lo0 = *(const bf16x8*)&Alo[(size_t)an0 * NF + ak];
        bf16x8 a_hi1 = *(const bf16x8*)&Ahi[(size_t)an1 * NF + ak];
        bf16x8 a_lo1 = *(const bf16x8*)&Alo[(size_t)an1 * NF + ak];

        bf16x8 bh[4], bl[4];
#pragma unroll
        for (int nt = 0; nt < 4; nt++) {
            int el = (nt * 512 + ks * 64 + l) * 8;
            bh[nt] = *(const bf16x8*)&wlds[el];
            bl[nt] = *(const bf16x8*)&wlds[16384 + el];
        }
#pragma unroll
        for (int nt = 0; nt < 4; nt++) {
            acc0[nt] = __builtin_amdgcn_mfma_f32_16x16x32_bf16(a_hi0, bh[nt], acc0[nt], 0, 0, 0);
            acc1[nt] = __builtin_amdgcn_mfma_f32_16x16x32_bf16(a_hi1, bh[nt], acc1[nt], 0, 0, 0);
        }
#pragma unroll
        for (int nt = 0; nt < 4; nt++) {
            acc0[nt] = __builtin_amdgcn_mfma_f32_16x16x32_bf16(a_hi0, bl[nt], acc0[nt], 0, 0, 0);
            acc1[nt] = __builtin_amdgcn_mfma_f32_16x16x32_bf16(a_hi1, bl[nt], acc1[nt], 0, 0, 0);
        }
#pragma unroll
        for (int nt = 0; nt < 4; nt++) {
            acc0[nt] = __builtin_amdgcn_mfma_f32_16x16x32_bf16(a_lo0, bh[nt], acc0[nt], 0, 0, 0);
            acc1[nt] = __builtin_amdgcn_mfma_f32_16x16x32_bf16(a_lo1, bh[nt], acc1[nt], 0, 0, 0);
        }
    }

    // ---- epilogue: bias + store. D: col=l&15 -> feature, row=kg*4+r -> node ----
#pragma unroll
    for (int nt = 0; nt < 4; nt++) {
        const int f = half * 64 + nt * 16 + arow;
        const float b = bias[f];
#pragma unroll
        for (int r = 0; r < 4; r++) {
            int n0 = nbase + kg * 4 + r;
            if (n0 < NN) Z[(size_t)n0 * NF + f] = acc0[nt][r] + b;
            int n1 = nbase + 16 + kg * 4 + r;
            if (n1 < NN) Z[(size_t)n1 * NF + f] = acc1[nt][r] + b;
        }
    }
}

// ---------------- per-feature stats over Z: sum and sum-of-squares ----------------
// grid 200, block 256: thread (g,f) sums rows blockIdx*500+g, step 2.
__global__ __launch_bounds__(256) void k_stats(const float* __restrict__ Z,
                                               float* __restrict__ stats) {
    int f = threadIdx.x & 127;
    int g = threadIdx.x >> 7;   // 0,1
    int rend = blockIdx.x * 500 + 500;
    float s = 0.f, q = 0.f;
    for (int r = blockIdx.x * 500 + g; r < rend; r += 2) {
        float v = Z[(size_t)r * NF + f];
        s += v; q += v * v;
    }
    atomicAdd(&stats[f], s);
    atomicAdd(&stats[NF + f], q);
}

// ---------------- GraphNorm + LeakyReLU (in-place) + bf16 hi/lo emit ----------------
__global__ __launch_bounds__(256) void k_norm(const float* __restrict__ stats,
                                              const float* __restrict__ gamma,
                                              const float* __restrict__ beta,
                                              const float* __restrict__ alpha,
                                              float* __restrict__ Z,
                                              unsigned short* __restrict__ zhi,
                                              unsigned short* __restrict__ zlo) {
    __shared__ float sc[NF], sh[NF];
    int tid = threadIdx.x;
    if (tid < NF) {
        float mean = stats[tid] * (1.0f / NN);
        float ex2 = stats[NF + tid] * (1.0f / NN);
        float a = alpha[tid];
        float am = a * mean;
        float var = ex2 - 2.f * am * mean + am * am;
        float inv = rsqrtf(var + GEPS);
        float g = gamma[tid] * inv;
        sc[tid] = g;
        sh[tid] = beta[tid] - g * am;
    }
    __syncthreads();
    int i = blockIdx.x * 256 + tid;
    float4 z = ((const float4*)Z)[i];
    int f = (i & 31) * 4;
    float r0 = sc[f + 0] * z.x + sh[f + 0]; r0 = r0 > 0.f ? r0 : NEGS * r0;
    float r1 = sc[f + 1] * z.y + sh[f + 1]; r1 = r1 > 0.f ? r1 : NEGS * r1;
    float r2 = sc[f + 2] * z.z + sh[f + 2]; r2 = r2 > 0.f ? r2 : NEGS * r2;
    float r3 = sc[f + 3] * z.w + sh[f + 3]; r3 = r3 > 0.f ? r3 : NEGS * r3;
    ((float4*)Z)[i] = make_float4(r0, r1, r2, r3);
    ushort4 h, lo;
    h.x = bf16_rn(r0); lo.x = bf16_rn(r0 - bf16_tf(h.x));
    h.y = bf16_rn(r1); lo.y = bf16_rn(r1 - bf16_tf(h.y));
    h.z = bf16_rn(r2); lo.z = bf16_rn(r2 - bf16_tf(h.z));
    h.w = bf16_rn(r3); lo.w = bf16_rn(r3 - bf16_tf(h.w));
    ((ushort4*)zhi)[i] = h;
    ((ushort4*)zlo)[i] = lo;
}

// ---------------- final layer ----------------
__global__ __launch_bounds__(256) void k_final(const unsigned short* __restrict__ mhi,
                                               const unsigned short* __restrict__ mlo,
                                               const unsigned short* __restrict__ hhi,
                                               const unsigned short* __restrict__ hlo,
                                               const float* __restrict__ Wlo_,
                                               const float* __restrict__ blo_,
                                               const float* __restrict__ Wro_,
                                               float* __restrict__ out) {
    __shared__ __align__(16) float W[NOUT][256];
    __shared__ float bb[NOUT];
    int tid = threadIdx.x;
    for (int i = tid; i < NOUT * 256; i += 256) {
        int o = i >> 8, k = i & 255;
        W[o][k] = (k < NF) ? Wlo_[o * NF + k] : Wro_[o * NF + (k - NF)];
    }
    if (tid < NOUT) bb[tid] = blo_[tid];
    __syncthreads();

    int node = blockIdx.x * 64 + (tid >> 2);
    int j = tid & 3;
    if (node >= NN) return;
    const unsigned short* shi = (j < 2) ? mhi : hhi;
    const unsigned short* slo = (j < 2) ? mlo : hlo;
    int kbase = (j & 1) * 64;
    const unsigned short* rh = &shi[(size_t)node * NF + kbase];
    const unsigned short* rl = &slo[(size_t)node * NF + kbase];
    float a0 = 0.f, a1 = 0.f, a2 = 0.f;
#pragma unroll
    for (int q = 0; q < 16; q++) {
        ushort4 vh = *(const ushort4*)&rh[q * 4];
        ushort4 vl = *(const ushort4*)&rl[q * 4];
        float v0 = bf16_tf(vh.x) + bf16_tf(vl.x);
        float v1 = bf16_tf(vh.y) + bf16_tf(vl.y);
        float v2 = bf16_tf(vh.z) + bf16_tf(vl.z);
        float v3 = bf16_tf(vh.w) + bf16_tf(vl.w);
        int k = j * 64 + q * 4;
        float4 w0 = *(const float4*)&W[0][k];
        float4 w1 = *(const float4*)&W[1][k];
        float4 w2 = *(const float4*)&W[2][k];
        a0 += v0 * w0.x + v1 * w0.y + v2 * w0.z + v3 * w0.w;
        a1 += v0 * w1.x + v1 * w1.y + v2 * w1.z + v3 * w1.w;
        a2 += v0 * w2.x + v1 * w2.y + v2 * w2.z + v3 * w2.w;
    }
    a0 += __shfl_down(a0, 2, 4); a0 += __shfl_down(a0, 1, 4);
    a1 += __shfl_down(a1, 2, 4); a1 += __shfl_down(a1, 1, 4);
    a2 += __shfl_down(a2, 2, 4); a2 += __shfl_down(a2, 1, 4);
    if (j == 0) {
        out[node * 3 + 0] = tanhf(a0 + bb[0]) * 0.5f;
        out[node * 3 + 1] = tanhf(a1 + bb[1]) * 0.5f;
        out[node * 3 + 2] = tanhf(a2 + bb[2]) * 0.5f;
    }
}

extern "C" void kernel_launch(void* const* d_in, const int* in_sizes, int n_in,
                              void* d_out, int out_size, void* d_ws, size_t ws_size,
                              hipStream_t stream) {
    const float* x     = (const float*)d_in[0];
    const int*   ei    = (const int*)d_in[1];
    const float* Wl    = (const float*)d_in[2];
    const float* bl    = (const float*)d_in[3];
    const float* Wr    = (const float*)d_in[4];
    const float* Wlo   = (const float*)d_in[5];
    const float* blo   = (const float*)d_in[6];
    const float* Wro   = (const float*)d_in[7];
    const float* gamma = (const float*)d_in[8];
    const float* beta  = (const float*)d_in[9];
    const float* alpha = (const float*)d_in[10];
    float* out = (float*)d_out;

    const int* esrc = ei;
    const int* edst = ei + NE;

    char* ws = (char*)d_ws;
    size_t off = 0;
    auto alloc = [&](size_t bytes) -> void* {
        void* p = ws + off;
        off += (bytes + 255) & ~(size_t)255;
        return p;
    };

    const int NB = (NN + 255) / 256;  // 391
    int*   counts  = (int*)alloc(NN * sizeof(int));
    int*   offsets = (int*)alloc((NN + 1) * sizeof(int));
    int*   cursor  = (int*)alloc(NN * sizeof(int));
    int*   bsums   = (int*)alloc(NB * sizeof(int));
    int*   csr     = (int*)alloc(NE * sizeof(int));
    unsigned short* mhi = (unsigned short*)alloc((size_t)NN * NF * 2);
    unsigned short* mlo = (unsigned short*)alloc((size_t)NN * NF * 2);
    unsigned short* hhi = (unsigned short*)alloc((size_t)NN * NF * 2);
    unsigned short* hlo = (unsigned short*)alloc((size_t)NN * NF * 2);
    float* hfp   = (float*)alloc((size_t)NN * NF * sizeof(float));
    unsigned short* whi6 = (unsigned short*)alloc((size_t)6 * NF * 256 * 2);
    unsigned short* wlo6 = (unsigned short*)alloc((size_t)6 * NF * 256 * 2);
    float* stats = (float*)alloc(6 * 2 * NF * sizeof(float));

    hipMemsetAsync(counts, 0, NN * sizeof(int), stream);
    hipMemsetAsync(stats, 0, 6 * 2 * NF * sizeof(float), stream);

    // CSR build
    k_hist<<<(NE + 255) / 256, 256, 0, stream>>>(edst, counts);
    k_scan1<<<NB, 256, 0, stream>>>(counts, bsums);
    k_scan2<<<1, 512, 0, stream>>>(bsums, NB);
    k_scan3<<<NB, 256, 0, stream>>>(counts, bsums, offsets, cursor);
    k_scatter<<<(NE + 255) / 256, 256, 0, stream>>>(esrc, edst, cursor, csr);

    // one-time splits
    k_wsplit<<<(6 * NF * 256 + 255) / 256, 256, 0, stream>>>(Wl, Wr, whi6, wlo6);
    k_xsplit<<<NN * NF / 4 / 256, 256, 0, stream>>>(x, hhi, hlo);

    const int aggGrid  = (NN + 1) / 2;
    const int gemmGridX = (NN + 255) / 256;  // 391
    const int normGrid = NN * NF / 4 / 256;  // 12500
    const int finGrid  = (NN + 63) / 64;

    const float* hcur = x;
    for (int L = 0; L < 6; ++L) {
        k_aggmax<<<aggGrid, 256, 0, stream>>>(hcur, offsets, csr, mhi, mlo);
        k_gemm<<<dim3(gemmGridX, 2), 512, 0, stream>>>(mhi, mlo, hhi, hlo,
                                                       whi6 + (size_t)L * NF * 256,
                                                       wlo6 + (size_t)L * NF * 256,
                                                       bl + (size_t)L * NF,
                                                       hfp);
        k_stats<<<200, 256, 0, stream>>>(hfp, stats + (size_t)L * 2 * NF);
        k_norm<<<normGrid, 256, 0, stream>>>(stats + (size_t)L * 2 * NF,
                                             gamma + (size_t)L * NF,
                                             beta + (size_t)L * NF,
                                             alpha + (size_t)L * NF,
                                             hfp, hhi, hlo);
        hcur = hfp;
    }
    // final layer
    k_aggmax<<<aggGrid, 256, 0, stream>>>(hcur, offsets, csr, mhi, mlo);
    k_final<<<finGrid, 256, 0, stream>>>(mhi, mlo, hhi, hlo, Wlo, blo, Wro, out);
}

// Round 6
// 1892.331 us; speedup vs baseline: 1.1323x; 1.0685x over previous
//
#include <hip/hip_runtime.h>
#include <math.h>

#define NN 100000
#define NE 1600000
#define NF 128
#define NOUT 3
#define NEGS 0.02f
#define GEPS 1e-5f

typedef __attribute__((ext_vector_type(8))) short bf16x8;
typedef __attribute__((ext_vector_type(4))) float f32x4;

__device__ __forceinline__ unsigned short bf16_rn(float f) {
    unsigned u = __float_as_uint(f);
    unsigned r = u + 0x7FFFu + ((u >> 16) & 1u);
    return (unsigned short)(r >> 16);
}
__device__ __forceinline__ float bf16_tf(unsigned short h) {
    return __uint_as_float((unsigned)h << 16);
}
// packed (hi,lo): hi in top 16 bits, lo in bottom. value = tf(hi)+tf(lo), err ~2^-17
__device__ __forceinline__ unsigned pk2(float v) {
    unsigned short hi = bf16_rn(v);
    unsigned short lo = bf16_rn(v - bf16_tf(hi));
    return ((unsigned)hi << 16) | lo;
}
__device__ __forceinline__ float unpk(unsigned u) {
    return __uint_as_float(u & 0xFFFF0000u) + __uint_as_float(u << 16);
}

// ---------------- CSR build ----------------
// hist also records each edge's rank within its dst bucket (atomic return value)
__global__ void k_hist(const int* __restrict__ dst, int* __restrict__ counts,
                       int* __restrict__ rank) {
    int i = blockIdx.x * blockDim.x + threadIdx.x;
    if (i < NE) rank[i] = atomicAdd(&counts[dst[i]], 1);
}

__global__ void k_scan1(const int* __restrict__ counts, int* __restrict__ bsums) {
    __shared__ int s[256];
    int i = blockIdx.x * 256 + threadIdx.x;
    s[threadIdx.x] = (i < NN) ? counts[i] : 0;
    __syncthreads();
    for (int off = 128; off > 0; off >>= 1) {
        if (threadIdx.x < off) s[threadIdx.x] += s[threadIdx.x + off];
        __syncthreads();
    }
    if (threadIdx.x == 0) bsums[blockIdx.x] = s[0];
}

__global__ void k_scan2(int* __restrict__ bsums, int nb) {
    __shared__ int s[512];
    int t = threadIdx.x;
    int v = (t < nb) ? bsums[t] : 0;
    s[t] = v;
    __syncthreads();
    for (int off = 1; off < 512; off <<= 1) {
        int u = (t >= off) ? s[t - off] : 0;
        __syncthreads();
        s[t] += u;
        __syncthreads();
    }
    if (t < nb) bsums[t] = s[t] - v;   // exclusive
}

__global__ void k_scan3(const int* __restrict__ counts, const int* __restrict__ bsums,
                        int* __restrict__ offsets) {
    __shared__ int s[256];
    int i = blockIdx.x * 256 + threadIdx.x;
    int v = (i < NN) ? counts[i] : 0;
    s[threadIdx.x] = v;
    __syncthreads();
    for (int off = 1; off < 256; off <<= 1) {
        int u = (threadIdx.x >= off) ? s[threadIdx.x - off] : 0;
        __syncthreads();
        s[threadIdx.x] += u;
        __syncthreads();
    }
    int excl = s[threadIdx.x] - v + bsums[blockIdx.x];
    if (i <= NN) offsets[i] = excl;
}

// atomic-free scatter: position = offsets[dst] + rank
__global__ void k_scatter(const int* __restrict__ src, const int* __restrict__ dst,
                          const int* __restrict__ offsets, const int* __restrict__ rank,
                          int* __restrict__ csr) {
    int i = blockIdx.x * blockDim.x + threadIdx.x;
    if (i < NE) csr[offsets[dst[i]] + rank[i]] = src[i];
}

// ---------------- weight split: Wcat[L][o][k] -> bf16 hi/lo ----------------
__global__ void k_wsplit(const float* __restrict__ Wl, const float* __restrict__ Wr,
                         unsigned short* __restrict__ whi, unsigned short* __restrict__ wlo) {
    int i = blockIdx.x * 256 + threadIdx.x;
    if (i >= 6 * NF * 256) return;
    int L = i >> 15;
    int rem = i & 32767;
    int o = rem >> 8;
    int k = rem & 255;
    float v = (k < NF) ? Wl[L * NF * NF + o * NF + k] : Wr[L * NF * NF + o * NF + (k - NF)];
    unsigned short h = bf16_rn(v);
    whi[i] = h;
    wlo[i] = bf16_rn(v - bf16_tf(h));
}

// ---------------- x pack (layer-0 h operand) ----------------
__global__ void k_xpack(const float* __restrict__ x, unsigned* __restrict__ hpk) {
    int i = blockIdx.x * 256 + threadIdx.x;   // over NN*NF/4 float4s
    float4 v = ((const float4*)x)[i];
    uint4 p;
    p.x = pk2(v.x); p.y = pk2(v.y); p.z = pk2(v.z); p.w = pk2(v.w);
    ((uint4*)hpk)[i] = p;
}

// ---------------- max aggregation (CSR): one wave per node, 2 feats/lane ----------------
__global__ __launch_bounds__(256) void k_aggmax(const unsigned* __restrict__ hpk,
                                                const int* __restrict__ offsets,
                                                const int* __restrict__ csr,
                                                unsigned* __restrict__ mpk) {
    int node = blockIdx.x * 4 + (threadIdx.x >> 6);
    int l = threadIdx.x & 63;
    int beg = offsets[node], end = offsets[node + 1];
    float aa = -INFINITY, ab = -INFINITY;
    int e = beg;
    for (; e + 4 <= end; e += 4) {
        int s0 = csr[e], s1 = csr[e + 1], s2 = csr[e + 2], s3 = csr[e + 3];
        uint2 g0 = *(const uint2*)&hpk[(size_t)s0 * NF + 2 * l];
        uint2 g1 = *(const uint2*)&hpk[(size_t)s1 * NF + 2 * l];
        uint2 g2 = *(const uint2*)&hpk[(size_t)s2 * NF + 2 * l];
        uint2 g3 = *(const uint2*)&hpk[(size_t)s3 * NF + 2 * l];
        aa = fmaxf(aa, fmaxf(fmaxf(unpk(g0.x), unpk(g1.x)), fmaxf(unpk(g2.x), unpk(g3.x))));
        ab = fmaxf(ab, fmaxf(fmaxf(unpk(g0.y), unpk(g1.y)), fmaxf(unpk(g2.y), unpk(g3.y))));
    }
    for (; e < end; ++e) {
        uint2 g = *(const uint2*)&hpk[(size_t)csr[e] * NF + 2 * l];
        aa = fmaxf(aa, unpk(g.x));
        ab = fmaxf(ab, unpk(g.y));
    }
    uint2 r;
    r.x = (beg == end) ? 0u : pk2(aa);
    r.y = (beg == end) ? 0u : pk2(ab);
    *(uint2*)&mpk[(size_t)node * NF + 2 * l] = r;
}

// ---------------- MFMA GEMM, weights resident in LDS (lane-linear fragment layout)
// grid (391, 2): x = 256-node tile, y = out-half (64 outs). 512 thr = 8 waves.
__global__ __launch_bounds__(512) void k_gemm(const unsigned* __restrict__ mpk,
                                              const unsigned* __restrict__ hpk,
                                              const unsigned short* __restrict__ whi,
                                              const unsigned short* __restrict__ wlo,
                                              const float* __restrict__ bias,
                                              unsigned* __restrict__ zpk) {
    __shared__ __align__(16) unsigned short wlds[32768];   // 64KB exactly
    const int tid = threadIdx.x;
    const int half = blockIdx.y;
    const int w = tid >> 6;
    const int l = tid & 63;
    const int arow = l & 15;
    const int kg = l >> 4;

    // ---- stage weights into fragment order (tid-linear LDS writes) ----
#pragma unroll
    for (int i = 0; i < 8; i++) {
        int gd = tid + i * 512;            // 0..4095
        int arr = gd >> 11;                // 0=hi, 1=lo
        int rem = gd & 2047;
        int nt = rem >> 9;                 // 0..3
        int ks = (rem >> 6) & 7;           // 0..7
        int ls = rem & 63;                 // lane slot
        int r = nt * 16 + (ls & 15);
        int g = ks * 4 + (ls >> 4);
        const unsigned short* srcw = arr ? wlo : whi;
        bf16x8 v = *(const bf16x8*)&srcw[(size_t)(half * 64 + r) * 256 + g * 8];
        *(bf16x8*)&wlds[arr * 16384 + rem * 8] = v;
    }
    __syncthreads();

    const int nbase = blockIdx.x * 256 + w * 32;
    int an0 = nbase + arow;      if (an0 > NN - 1) an0 = NN - 1;
    int an1 = nbase + 16 + arow; if (an1 > NN - 1) an1 = NN - 1;

    f32x4 acc0[4], acc1[4];
#pragma unroll
    for (int nt = 0; nt < 4; nt++) {
        acc0[nt] = (f32x4){0.f, 0.f, 0.f, 0.f};
        acc1[nt] = (f32x4){0.f, 0.f, 0.f, 0.f};
    }

    union U { uint4 u; bf16x8 v; };

#pragma unroll
    for (int ks = 0; ks < 8; ks++) {
        const unsigned* A = (ks < 4) ? mpk : hpk;
        const int ak = (ks & 3) * 32 + kg * 8;
        uint4 p0 = *(const uint4*)&A[(size_t)an0 * NF + ak];
        uint4 p1 = *(const uint4*)&A[(size_t)an0 * NF + ak + 4];
        uint4 q0 = *(const uint4*)&A[(size_t)an1 * NF + ak];
        uint4 q1 = *(const uint4*)&A[(size_t)an1 * NF + ak + 4];

        U ah0, al0, ah1, al1;
        ah0.u.x = (p0.x >> 16) | (p0.y & 0xFFFF0000u);
        ah0.u.y = (p0.z >> 16) | (p0.w & 0xFFFF0000u);
        ah0.u.z = (p1.x >> 16) | (p1.y & 0xFFFF0000u);
        ah0.u.w = (p1.z >> 16) | (p1.w & 0xFFFF0000u);
        al0.u.x = (p0.x & 0xFFFFu) | (p0.y << 16);
        al0.u.y = (p0.z & 0xFFFFu) | (p0.w << 16);
        al0.u.z = (p1.x & 0xFFFFu) | (p1.y << 16);
        al0.u.w = (p1.z & 0xFFFFu) | (p1.w << 16);
        ah1.u.x = (q0.x >> 16) | (q0.y & 0xFFFF0000u);
        ah1.u.y = (q0.z >> 16) | (q0.w & 0xFFFF0000u);
        ah1.u.z = (q1.x >> 16) | (q1.y & 0xFFFF0000u);
        ah1.u.w = (q1.z >> 16) | (q1.w & 0xFFFF0000u);
        al1.u.x = (q0.x & 0xFFFFu) | (q0.y << 16);
        al1.u.y = (q0.z & 0xFFFFu) | (q0.w << 16);
        al1.u.z = (q1.x & 0xFFFFu) | (q1.y << 16);
        al1.u.w = (q1.z & 0xFFFFu) | (q1.w << 16);

        bf16x8 bh[4], bl[4];
#pragma unroll
        for (int nt = 0; nt < 4; nt++) {
            int el = (nt * 512 + ks * 64 + l) * 8;
            bh[nt] = *(const bf16x8*)&wlds[el];
            bl[nt] = *(const bf16x8*)&wlds[16384 + el];
        }
#pragma unroll
        for (int nt = 0; nt < 4; nt++) {
            acc0[nt] = __builtin_amdgcn_mfma_f32_16x16x32_bf16(ah0.v, bh[nt], acc0[nt], 0, 0, 0);
            acc1[nt] = __builtin_amdgcn_mfma_f32_16x16x32_bf16(ah1.v, bh[nt], acc1[nt], 0, 0, 0);
        }
#pragma unroll
        for (int nt = 0; nt < 4; nt++) {
            acc0[nt] = __builtin_amdgcn_mfma_f32_16x16x32_bf16(ah0.v, bl[nt], acc0[nt], 0, 0, 0);
            acc1[nt] = __builtin_amdgcn_mfma_f32_16x16x32_bf16(ah1.v, bl[nt], acc1[nt], 0, 0, 0);
        }
#pragma unroll
        for (int nt = 0; nt < 4; nt++) {
            acc0[nt] = __builtin_amdgcn_mfma_f32_16x16x32_bf16(al0.v, bh[nt], acc0[nt], 0, 0, 0);
            acc1[nt] = __builtin_amdgcn_mfma_f32_16x16x32_bf16(al1.v, bh[nt], acc1[nt], 0, 0, 0);
        }
    }

    // ---- epilogue: bias + packed store. D: col=l&15 -> feature, row=kg*4+r -> node ----
#pragma unroll
    for (int nt = 0; nt < 4; nt++) {
        const int f = half * 64 + nt * 16 + arow;
        const float b = bias[f];
#pragma unroll
        for (int r = 0; r < 4; r++) {
            int n0 = nbase + kg * 4 + r;
            if (n0 < NN) zpk[(size_t)n0 * NF + f] = pk2(acc0[nt][r] + b);
            int n1 = nbase + 16 + kg * 4 + r;
            if (n1 < NN) zpk[(size_t)n1 * NF + f] = pk2(acc1[nt][r] + b);
        }
    }
}

// ---------------- per-feature stats over zpk: sum and sum-of-squares ----------------
__global__ __launch_bounds__(256) void k_stats(const unsigned* __restrict__ zpk,
                                               float* __restrict__ stats) {
    int f = threadIdx.x & 127;
    int g = threadIdx.x >> 7;   // 0,1
    int rend = blockIdx.x * 500 + 500;
    float s = 0.f, q = 0.f;
    for (int r = blockIdx.x * 500 + g; r < rend; r += 2) {
        float v = unpk(zpk[(size_t)r * NF + f]);
        s += v; q += v * v;
    }
    atomicAdd(&stats[f], s);
    atomicAdd(&stats[NF + f], q);
}

// ---------------- GraphNorm + LeakyReLU: zpk -> hpk ----------------
__global__ __launch_bounds__(256) void k_norm(const float* __restrict__ stats,
                                              const float* __restrict__ gamma,
                                              const float* __restrict__ beta,
                                              const float* __restrict__ alpha,
                                              const unsigned* __restrict__ zpk,
                                              unsigned* __restrict__ hpk) {
    __shared__ float sc[NF], sh[NF];
    int tid = threadIdx.x;
    if (tid < NF) {
        float mean = stats[tid] * (1.0f / NN);
        float ex2 = stats[NF + tid] * (1.0f / NN);
        float a = alpha[tid];
        float am = a * mean;
        float var = ex2 - 2.f * am * mean + am * am;
        float inv = rsqrtf(var + GEPS);
        float g = gamma[tid] * inv;
        sc[tid] = g;
        sh[tid] = beta[tid] - g * am;
    }
    __syncthreads();
    int i = blockIdx.x * 256 + tid;   // NN*NF/4 uint4 units
    uint4 z = ((const uint4*)zpk)[i];
    int f = (i & 31) * 4;
    float r0 = sc[f + 0] * unpk(z.x) + sh[f + 0]; r0 = r0 > 0.f ? r0 : NEGS * r0;
    float r1 = sc[f + 1] * unpk(z.y) + sh[f + 1]; r1 = r1 > 0.f ? r1 : NEGS * r1;
    float r2 = sc[f + 2] * unpk(z.z) + sh[f + 2]; r2 = r2 > 0.f ? r2 : NEGS * r2;
    float r3 = sc[f + 3] * unpk(z.w) + sh[f + 3]; r3 = r3 > 0.f ? r3 : NEGS * r3;
    uint4 p;
    p.x = pk2(r0); p.y = pk2(r1); p.z = pk2(r2); p.w = pk2(r3);
    ((uint4*)hpk)[i] = p;
}

// ---------------- final layer: out = tanh([m|h] @ Wcat_out.T + b)*0.5 ----------------
__global__ __launch_bounds__(256) void k_final(const unsigned* __restrict__ mpk,
                                               const unsigned* __restrict__ hpk,
                                               const float* __restrict__ Wlo_,
                                               const float* __restrict__ blo_,
                                               const float* __restrict__ Wro_,
                                               float* __restrict__ out) {
    __shared__ __align__(16) float W[NOUT][256];
    __shared__ float bb[NOUT];
    int tid = threadIdx.x;
    for (int i = tid; i < NOUT * 256; i += 256) {
        int o = i >> 8, k = i & 255;
        W[o][k] = (k < NF) ? Wlo_[o * NF + k] : Wro_[o * NF + (k - NF)];
    }
    if (tid < NOUT) bb[tid] = blo_[tid];
    __syncthreads();

    int node = blockIdx.x * 64 + (tid >> 2);
    int j = tid & 3;
    if (node >= NN) return;
    const unsigned* sp = (j < 2) ? mpk : hpk;
    int kbase = (j & 1) * 64;
    const unsigned* rp = &sp[(size_t)node * NF + kbase];
    float a0 = 0.f, a1 = 0.f, a2 = 0.f;
#pragma unroll
    for (int q = 0; q < 16; q++) {
        uint4 u = *(const uint4*)&rp[q * 4];
        float v0 = unpk(u.x), v1 = unpk(u.y), v2 = unpk(u.z), v3 = unpk(u.w);
        int k = j * 64 + q * 4;
        float4 w0 = *(const float4*)&W[0][k];
        float4 w1 = *(const float4*)&W[1][k];
        float4 w2 = *(const float4*)&W[2][k];
        a0 += v0 * w0.x + v1 * w0.y + v2 * w0.z + v3 * w0.w;
        a1 += v0 * w1.x + v1 * w1.y + v2 * w1.z + v3 * w1.w;
        a2 += v0 * w2.x + v1 * w2.y + v2 * w2.z + v3 * w2.w;
    }
    a0 += __shfl_down(a0, 2, 4); a0 += __shfl_down(a0, 1, 4);
    a1 += __shfl_down(a1, 2, 4); a1 += __shfl_down(a1, 1, 4);
    a2 += __shfl_down(a2, 2, 4); a2 += __shfl_down(a2, 1, 4);
    if (j == 0) {
        out[node * 3 + 0] = tanhf(a0 + bb[0]) * 0.5f;
        out[node * 3 + 1] = tanhf(a1 + bb[1]) * 0.5f;
        out[node * 3 + 2] = tanhf(a2 + bb[2]) * 0.5f;
    }
}

extern "C" void kernel_launch(void* const* d_in, const int* in_sizes, int n_in,
                              void* d_out, int out_size, void* d_ws, size_t ws_size,
                              hipStream_t stream) {
    const float* x     = (const float*)d_in[0];
    const int*   ei    = (const int*)d_in[1];
    const float* Wl    = (const float*)d_in[2];
    const float* bl    = (const float*)d_in[3];
    const float* Wr    = (const float*)d_in[4];
    const float* Wlo   = (const float*)d_in[5];
    const float* blo   = (const float*)d_in[6];
    const float* Wro   = (const float*)d_in[7];
    const float* gamma = (const float*)d_in[8];
    const float* beta  = (const float*)d_in[9];
    const float* alpha = (const float*)d_in[10];
    float* out = (float*)d_out;

    const int* esrc = ei;
    const int* edst = ei + NE;

    char* ws = (char*)d_ws;
    size_t off = 0;
    auto alloc = [&](size_t bytes) -> void* {
        void* p = ws + off;
        off += (bytes + 255) & ~(size_t)255;
        return p;
    };

    const int NB = (NN + 255) / 256;  // 391
    int*      counts  = (int*)alloc(NN * sizeof(int));
    int*      offsets = (int*)alloc((NN + 1) * sizeof(int));
    int*      bsums   = (int*)alloc(NB * sizeof(int));
    int*      rank    = (int*)alloc(NE * sizeof(int));
    int*      csr     = (int*)alloc(NE * sizeof(int));
    unsigned* mpk     = (unsigned*)alloc((size_t)NN * NF * 4);
    unsigned* hpk     = (unsigned*)alloc((size_t)NN * NF * 4);
    unsigned* zpk     = (unsigned*)alloc((size_t)NN * NF * 4);
    unsigned short* whi6 = (unsigned short*)alloc((size_t)6 * NF * 256 * 2);
    unsigned short* wlo6 = (unsigned short*)alloc((size_t)6 * NF * 256 * 2);
    float*    stats   = (float*)alloc(6 * 2 * NF * sizeof(float));

    hipMemsetAsync(counts, 0, NN * sizeof(int), stream);
    hipMemsetAsync(stats, 0, 6 * 2 * NF * sizeof(float), stream);

    // CSR build (atomic-free scatter via rank)
    k_hist<<<(NE + 255) / 256, 256, 0, stream>>>(edst, counts, rank);
    k_scan1<<<NB, 256, 0, stream>>>(counts, bsums);
    k_scan2<<<1, 512, 0, stream>>>(bsums, NB);
    k_scan3<<<NB, 256, 0, stream>>>(counts, bsums, offsets);
    k_scatter<<<(NE + 255) / 256, 256, 0, stream>>>(esrc, edst, offsets, rank, csr);

    // one-time packs/splits
    k_wsplit<<<(6 * NF * 256 + 255) / 256, 256, 0, stream>>>(Wl, Wr, whi6, wlo6);
    k_xpack<<<NN * NF / 4 / 256, 256, 0, stream>>>(x, hpk);

    const int aggGrid   = NN / 4;            // 25000
    const int gemmGridX = (NN + 255) / 256;  // 391
    const int normGrid  = NN * NF / 4 / 256; // 12500
    const int finGrid   = (NN + 63) / 64;

    for (int L = 0; L < 6; ++L) {
        k_aggmax<<<aggGrid, 256, 0, stream>>>(hpk, offsets, csr, mpk);
        k_gemm<<<dim3(gemmGridX, 2), 512, 0, stream>>>(mpk, hpk,
                                                       whi6 + (size_t)L * NF * 256,
                                                       wlo6 + (size_t)L * NF * 256,
                                                       bl + (size_t)L * NF,
                                                       zpk);
        k_stats<<<200, 256, 0, stream>>>(zpk, stats + (size_t)L * 2 * NF);
        k_norm<<<normGrid, 256, 0, stream>>>(stats + (size_t)L * 2 * NF,
                                             gamma + (size_t)L * NF,
                                             beta + (size_t)L * NF,
                                             alpha + (size_t)L * NF,
                                             zpk, hpk);
    }
    // final layer
    k_aggmax<<<aggGrid, 256, 0, stream>>>(hpk, offsets, csr, mpk);
    k_final<<<finGrid, 256, 0, stream>>>(mpk, hpk, Wlo, blo, Wro, out);
}

// Round 8
// 1506.218 us; speedup vs baseline: 1.4226x; 1.2563x over previous
//
#include <hip/hip_runtime.h>
#include <math.h>

#define NN 100000
#define NE 1600000
#define NF 128
#define NOUT 3
#define NEGS 0.02f
#define GEPS 1e-5f

typedef __attribute__((ext_vector_type(8))) short bf16x8;
typedef __attribute__((ext_vector_type(4))) float f32x4;

__device__ __forceinline__ unsigned short bf16_rn(float f) {
    unsigned u = __float_as_uint(f);
    unsigned r = u + 0x7FFFu + ((u >> 16) & 1u);
    return (unsigned short)(r >> 16);
}
__device__ __forceinline__ float bf16_tf(unsigned short h) {
    return __uint_as_float((unsigned)h << 16);
}
// packed (hi,lo): hi in top 16 bits, lo in bottom. value = tf(hi)+tf(lo), err ~2^-17
__device__ __forceinline__ unsigned pk2(float v) {
    unsigned short hi = bf16_rn(v);
    unsigned short lo = bf16_rn(v - bf16_tf(hi));
    return ((unsigned)hi << 16) | lo;
}
__device__ __forceinline__ float unpk(unsigned u) {
    return __uint_as_float(u & 0xFFFF0000u) + __uint_as_float(u << 16);
}

// ---------------- CSR build ----------------
__global__ void k_hist(const int* __restrict__ dst, int* __restrict__ counts,
                       int* __restrict__ rank) {
    int i = blockIdx.x * blockDim.x + threadIdx.x;
    if (i < NE) rank[i] = atomicAdd(&counts[dst[i]], 1);
}

__global__ void k_scan1(const int* __restrict__ counts, int* __restrict__ bsums) {
    __shared__ int s[256];
    int i = blockIdx.x * 256 + threadIdx.x;
    s[threadIdx.x] = (i < NN) ? counts[i] : 0;
    __syncthreads();
    for (int off = 128; off > 0; off >>= 1) {
        if (threadIdx.x < off) s[threadIdx.x] += s[threadIdx.x + off];
        __syncthreads();
    }
    if (threadIdx.x == 0) bsums[blockIdx.x] = s[0];
}

__global__ void k_scan2(int* __restrict__ bsums, int nb) {
    __shared__ int s[512];
    int t = threadIdx.x;
    int v = (t < nb) ? bsums[t] : 0;
    s[t] = v;
    __syncthreads();
    for (int off = 1; off < 512; off <<= 1) {
        int u = (t >= off) ? s[t - off] : 0;
        __syncthreads();
        s[t] += u;
        __syncthreads();
    }
    if (t < nb) bsums[t] = s[t] - v;   // exclusive
}

__global__ void k_scan3(const int* __restrict__ counts, const int* __restrict__ bsums,
                        int* __restrict__ offsets) {
    __shared__ int s[256];
    int i = blockIdx.x * 256 + threadIdx.x;
    int v = (i < NN) ? counts[i] : 0;
    s[threadIdx.x] = v;
    __syncthreads();
    for (int off = 1; off < 256; off <<= 1) {
        int u = (threadIdx.x >= off) ? s[threadIdx.x - off] : 0;
        __syncthreads();
        s[threadIdx.x] += u;
        __syncthreads();
    }
    int excl = s[threadIdx.x] - v + bsums[blockIdx.x];
    if (i <= NN) offsets[i] = excl;
}

__global__ void k_scatter(const int* __restrict__ src, const int* __restrict__ dst,
                          const int* __restrict__ offsets, const int* __restrict__ rank,
                          int* __restrict__ csr) {
    int i = blockIdx.x * blockDim.x + threadIdx.x;
    if (i < NE) csr[offsets[dst[i]] + rank[i]] = src[i];
}

// ---------------- weight split ----------------
__global__ void k_wsplit(const float* __restrict__ Wl, const float* __restrict__ Wr,
                         unsigned short* __restrict__ whi, unsigned short* __restrict__ wlo) {
    int i = blockIdx.x * 256 + threadIdx.x;
    if (i >= 6 * NF * 256) return;
    int L = i >> 15;
    int rem = i & 32767;
    int o = rem >> 8;
    int k = rem & 255;
    float v = (k < NF) ? Wl[L * NF * NF + o * NF + k] : Wr[L * NF * NF + o * NF + (k - NF)];
    unsigned short h = bf16_rn(v);
    whi[i] = h;
    wlo[i] = bf16_rn(v - bf16_tf(h));
}

// ---------------- x pack ----------------
__global__ void k_xpack(const float* __restrict__ x, unsigned* __restrict__ hpk) {
    int i = blockIdx.x * 256 + threadIdx.x;
    float4 v = ((const float4*)x)[i];
    uint4 p;
    p.x = pk2(v.x); p.y = pk2(v.y); p.z = pk2(v.z); p.w = pk2(v.w);
    ((uint4*)hpk)[i] = p;
}

// ---------------- max aggregation: one wave per node, 2 feats/lane, 8-edge unroll ----------------
__global__ __launch_bounds__(256) void k_aggmax(const unsigned* __restrict__ hpk,
                                                const int* __restrict__ offsets,
                                                const int* __restrict__ csr,
                                                unsigned* __restrict__ mpk) {
    int node = blockIdx.x * 4 + (threadIdx.x >> 6);
    int l = threadIdx.x & 63;
    int beg = offsets[node], end = offsets[node + 1];
    float aa = -INFINITY, ab = -INFINITY;
    int e = beg;
    for (; e + 8 <= end; e += 8) {
        int s0 = csr[e],     s1 = csr[e + 1], s2 = csr[e + 2], s3 = csr[e + 3];
        int s4 = csr[e + 4], s5 = csr[e + 5], s6 = csr[e + 6], s7 = csr[e + 7];
        uint2 g0 = *(const uint2*)&hpk[(size_t)s0 * NF + 2 * l];
        uint2 g1 = *(const uint2*)&hpk[(size_t)s1 * NF + 2 * l];
        uint2 g2 = *(const uint2*)&hpk[(size_t)s2 * NF + 2 * l];
        uint2 g3 = *(const uint2*)&hpk[(size_t)s3 * NF + 2 * l];
        uint2 g4 = *(const uint2*)&hpk[(size_t)s4 * NF + 2 * l];
        uint2 g5 = *(const uint2*)&hpk[(size_t)s5 * NF + 2 * l];
        uint2 g6 = *(const uint2*)&hpk[(size_t)s6 * NF + 2 * l];
        uint2 g7 = *(const uint2*)&hpk[(size_t)s7 * NF + 2 * l];
        float m0 = fmaxf(fmaxf(unpk(g0.x), unpk(g1.x)), fmaxf(unpk(g2.x), unpk(g3.x)));
        float m1 = fmaxf(fmaxf(unpk(g4.x), unpk(g5.x)), fmaxf(unpk(g6.x), unpk(g7.x)));
        float n0 = fmaxf(fmaxf(unpk(g0.y), unpk(g1.y)), fmaxf(unpk(g2.y), unpk(g3.y)));
        float n1 = fmaxf(fmaxf(unpk(g4.y), unpk(g5.y)), fmaxf(unpk(g6.y), unpk(g7.y)));
        aa = fmaxf(aa, fmaxf(m0, m1));
        ab = fmaxf(ab, fmaxf(n0, n1));
    }
    for (; e + 4 <= end; e += 4) {
        int s0 = csr[e], s1 = csr[e + 1], s2 = csr[e + 2], s3 = csr[e + 3];
        uint2 g0 = *(const uint2*)&hpk[(size_t)s0 * NF + 2 * l];
        uint2 g1 = *(const uint2*)&hpk[(size_t)s1 * NF + 2 * l];
        uint2 g2 = *(const uint2*)&hpk[(size_t)s2 * NF + 2 * l];
        uint2 g3 = *(const uint2*)&hpk[(size_t)s3 * NF + 2 * l];
        aa = fmaxf(aa, fmaxf(fmaxf(unpk(g0.x), unpk(g1.x)), fmaxf(unpk(g2.x), unpk(g3.x))));
        ab = fmaxf(ab, fmaxf(fmaxf(unpk(g0.y), unpk(g1.y)), fmaxf(unpk(g2.y), unpk(g3.y))));
    }
    for (; e < end; ++e) {
        uint2 g = *(const uint2*)&hpk[(size_t)csr[e] * NF + 2 * l];
        aa = fmaxf(aa, unpk(g.x));
        ab = fmaxf(ab, unpk(g.y));
    }
    uint2 r;
    r.x = (beg == end) ? 0u : pk2(aa);
    r.y = (beg == end) ? 0u : pk2(ab);
    *(uint2*)&mpk[(size_t)node * NF + 2 * l] = r;
}

// ---------------- MFMA GEMM + fused per-feature stats ----------------
// grid (391, 2): x = 256-node tile, y = out-half (64 outs). 512 thr = 8 waves.
__global__ __launch_bounds__(512) void k_gemm(const unsigned* __restrict__ mpk,
                                              const unsigned* __restrict__ hpk,
                                              const unsigned short* __restrict__ whi,
                                              const unsigned short* __restrict__ wlo,
                                              const float* __restrict__ bias,
                                              unsigned* __restrict__ zpk,
                                              float* __restrict__ stats) {
    __shared__ __align__(16) unsigned short wlds[32768];   // 64KB
    __shared__ float redS[64], redQ[64];
    const int tid = threadIdx.x;
    const int half = blockIdx.y;
    const int w = tid >> 6;
    const int l = tid & 63;
    const int arow = l & 15;
    const int kg = l >> 4;

    if (tid < 64) { redS[tid] = 0.f; redQ[tid] = 0.f; }

    // ---- stage weights into fragment order (tid-linear LDS writes) ----
#pragma unroll
    for (int i = 0; i < 8; i++) {
        int gd = tid + i * 512;
        int arr = gd >> 11;
        int rem = gd & 2047;
        int nt = rem >> 9;
        int ks = (rem >> 6) & 7;
        int ls = rem & 63;
        int r = nt * 16 + (ls & 15);
        int g = ks * 4 + (ls >> 4);
        const unsigned short* srcw = arr ? wlo : whi;
        bf16x8 v = *(const bf16x8*)&srcw[(size_t)(half * 64 + r) * 256 + g * 8];
        *(bf16x8*)&wlds[arr * 16384 + rem * 8] = v;
    }
    __syncthreads();

    const int nbase = blockIdx.x * 256 + w * 32;
    int an0 = nbase + arow;      if (an0 > NN - 1) an0 = NN - 1;
    int an1 = nbase + 16 + arow; if (an1 > NN - 1) an1 = NN - 1;

    f32x4 acc0[4], acc1[4];
#pragma unroll
    for (int nt = 0; nt < 4; nt++) {
        acc0[nt] = (f32x4){0.f, 0.f, 0.f, 0.f};
        acc1[nt] = (f32x4){0.f, 0.f, 0.f, 0.f};
    }

    union U { uint4 u; bf16x8 v; };

#pragma unroll
    for (int ks = 0; ks < 8; ks++) {
        const unsigned* A = (ks < 4) ? mpk : hpk;
        const int ak = (ks & 3) * 32 + kg * 8;
        uint4 p0 = *(const uint4*)&A[(size_t)an0 * NF + ak];
        uint4 p1 = *(const uint4*)&A[(size_t)an0 * NF + ak + 4];
        uint4 q0 = *(const uint4*)&A[(size_t)an1 * NF + ak];
        uint4 q1 = *(const uint4*)&A[(size_t)an1 * NF + ak + 4];

        U ah0, al0, ah1, al1;
        ah0.u.x = (p0.x >> 16) | (p0.y & 0xFFFF0000u);
        ah0.u.y = (p0.z >> 16) | (p0.w & 0xFFFF0000u);
        ah0.u.z = (p1.x >> 16) | (p1.y & 0xFFFF0000u);
        ah0.u.w = (p1.z >> 16) | (p1.w & 0xFFFF0000u);
        al0.u.x = (p0.x & 0xFFFFu) | (p0.y << 16);
        al0.u.y = (p0.z & 0xFFFFu) | (p0.w << 16);
        al0.u.z = (p1.x & 0xFFFFu) | (p1.y << 16);
        al0.u.w = (p1.z & 0xFFFFu) | (p1.w << 16);
        ah1.u.x = (q0.x >> 16) | (q0.y & 0xFFFF0000u);
        ah1.u.y = (q0.z >> 16) | (q0.w & 0xFFFF0000u);
        ah1.u.z = (q1.x >> 16) | (q1.y & 0xFFFF0000u);
        ah1.u.w = (q1.z >> 16) | (q1.w & 0xFFFF0000u);
        al1.u.x = (q0.x & 0xFFFFu) | (q0.y << 16);
        al1.u.y = (q0.z & 0xFFFFu) | (q0.w << 16);
        al1.u.z = (q1.x & 0xFFFFu) | (q1.y << 16);
        al1.u.w = (q1.z & 0xFFFFu) | (q1.w << 16);

        bf16x8 bh[4], bl[4];
#pragma unroll
        for (int nt = 0; nt < 4; nt++) {
            int el = (nt * 512 + ks * 64 + l) * 8;
            bh[nt] = *(const bf16x8*)&wlds[el];
            bl[nt] = *(const bf16x8*)&wlds[16384 + el];
        }
#pragma unroll
        for (int nt = 0; nt < 4; nt++) {
            acc0[nt] = __builtin_amdgcn_mfma_f32_16x16x32_bf16(ah0.v, bh[nt], acc0[nt], 0, 0, 0);
            acc1[nt] = __builtin_amdgcn_mfma_f32_16x16x32_bf16(ah1.v, bh[nt], acc1[nt], 0, 0, 0);
        }
#pragma unroll
        for (int nt = 0; nt < 4; nt++) {
            acc0[nt] = __builtin_amdgcn_mfma_f32_16x16x32_bf16(ah0.v, bl[nt], acc0[nt], 0, 0, 0);
            acc1[nt] = __builtin_amdgcn_mfma_f32_16x16x32_bf16(ah1.v, bl[nt], acc1[nt], 0, 0, 0);
        }
#pragma unroll
        for (int nt = 0; nt < 4; nt++) {
            acc0[nt] = __builtin_amdgcn_mfma_f32_16x16x32_bf16(al0.v, bh[nt], acc0[nt], 0, 0, 0);
            acc1[nt] = __builtin_amdgcn_mfma_f32_16x16x32_bf16(al1.v, bh[nt], acc1[nt], 0, 0, 0);
        }
    }

    // ---- epilogue: bias + packed store + fused stats ----
#pragma unroll
    for (int nt = 0; nt < 4; nt++) {
        const int f = half * 64 + nt * 16 + arow;
        const float b = bias[f];
        float s = 0.f, q = 0.f;
#pragma unroll
        for (int r = 0; r < 4; r++) {
            int n0 = nbase + kg * 4 + r;
            float v0 = acc0[nt][r] + b;
            if (n0 < NN) { zpk[(size_t)n0 * NF + f] = pk2(v0); s += v0; q += v0 * v0; }
            int n1 = nbase + 16 + kg * 4 + r;
            float v1 = acc1[nt][r] + b;
            if (n1 < NN) { zpk[(size_t)n1 * NF + f] = pk2(v1); s += v1; q += v1 * v1; }
        }
        s += __shfl_xor(s, 16); s += __shfl_xor(s, 32);
        q += __shfl_xor(q, 16); q += __shfl_xor(q, 32);
        if (l < 16) {
            atomicAdd(&redS[nt * 16 + l], s);
            atomicAdd(&redQ[nt * 16 + l], q);
        }
    }
    __syncthreads();
    if (tid < 64) {
        atomicAdd(&stats[half * 64 + tid], redS[tid]);
        atomicAdd(&stats[NF + half * 64 + tid], redQ[tid]);
    }
}

// ---------------- GraphNorm + LeakyReLU: zpk -> hpk ----------------
__global__ __launch_bounds__(256) void k_norm(const float* __restrict__ stats,
                                              const float* __restrict__ gamma,
                                              const float* __restrict__ beta,
                                              const float* __restrict__ alpha,
                                              const unsigned* __restrict__ zpk,
                                              unsigned* __restrict__ hpk) {
    __shared__ float sc[NF], sh[NF];
    int tid = threadIdx.x;
    if (tid < NF) {
        float mean = stats[tid] * (1.0f / NN);
        float ex2 = stats[NF + tid] * (1.0f / NN);
        float a = alpha[tid];
        float am = a * mean;
        float var = ex2 - 2.f * am * mean + am * am;
        float inv = rsqrtf(var + GEPS);
        float g = gamma[tid] * inv;
        sc[tid] = g;
        sh[tid] = beta[tid] - g * am;
    }
    __syncthreads();
    int i = blockIdx.x * 256 + tid;
    uint4 z = ((const uint4*)zpk)[i];
    int f = (i & 31) * 4;
    float r0 = sc[f + 0] * unpk(z.x) + sh[f + 0]; r0 = r0 > 0.f ? r0 : NEGS * r0;
    float r1 = sc[f + 1] * unpk(z.y) + sh[f + 1]; r1 = r1 > 0.f ? r1 : NEGS * r1;
    float r2 = sc[f + 2] * unpk(z.z) + sh[f + 2]; r2 = r2 > 0.f ? r2 : NEGS * r2;
    float r3 = sc[f + 3] * unpk(z.w) + sh[f + 3]; r3 = r3 > 0.f ? r3 : NEGS * r3;
    uint4 p;
    p.x = pk2(r0); p.y = pk2(r1); p.z = pk2(r2); p.w = pk2(r3);
    ((uint4*)hpk)[i] = p;
}

// ---------------- final layer ----------------
__global__ __launch_bounds__(256) void k_final(const unsigned* __restrict__ mpk,
                                               const unsigned* __restrict__ hpk,
                                               const float* __restrict__ Wlo_,
                                               const float* __restrict__ blo_,
                                               const float* __restrict__ Wro_,
                                               float* __restrict__ out) {
    __shared__ __align__(16) float W[NOUT][256];
    __shared__ float bb[NOUT];
    int tid = threadIdx.x;
    for (int i = tid; i < NOUT * 256; i += 256) {
        int o = i >> 8, k = i & 255;
        W[o][k] = (k < NF) ? Wlo_[o * NF + k] : Wro_[o * NF + (k - NF)];
    }
    if (tid < NOUT) bb[tid] = blo_[tid];
    __syncthreads();

    int node = blockIdx.x * 64 + (tid >> 2);
    int j = tid & 3;
    if (node >= NN) return;
    const unsigned* sp = (j < 2) ? mpk : hpk;
    int kbase = (j & 1) * 64;
    const unsigned* rp = &sp[(size_t)node * NF + kbase];
    float a0 = 0.f, a1 = 0.f, a2 = 0.f;
#pragma unroll
    for (int q = 0; q < 16; q++) {
        uint4 u = *(const uint4*)&rp[q * 4];
        float v0 = unpk(u.x), v1 = unpk(u.y), v2 = unpk(u.z), v3 = unpk(u.w);
        int k = j * 64 + q * 4;
        float4 w0 = *(const float4*)&W[0][k];
        float4 w1 = *(const float4*)&W[1][k];
        float4 w2 = *(const float4*)&W[2][k];
        a0 += v0 * w0.x + v1 * w0.y + v2 * w0.z + v3 * w0.w;
        a1 += v0 * w1.x + v1 * w1.y + v2 * w1.z + v3 * w1.w;
        a2 += v0 * w2.x + v1 * w2.y + v2 * w2.z + v3 * w2.w;
    }
    a0 += __shfl_down(a0, 2, 4); a0 += __shfl_down(a0, 1, 4);
    a1 += __shfl_down(a1, 2, 4); a1 += __shfl_down(a1, 1, 4);
    a2 += __shfl_down(a2, 2, 4); a2 += __shfl_down(a2, 1, 4);
    if (j == 0) {
        out[node * 3 + 0] = tanhf(a0 + bb[0]) * 0.5f;
        out[node * 3 + 1] = tanhf(a1 + bb[1]) * 0.5f;
        out[node * 3 + 2] = tanhf(a2 + bb[2]) * 0.5f;
    }
}

extern "C" void kernel_launch(void* const* d_in, const int* in_sizes, int n_in,
                              void* d_out, int out_size, void* d_ws, size_t ws_size,
                              hipStream_t stream) {
    const float* x     = (const float*)d_in[0];
    const int*   ei    = (const int*)d_in[1];
    const float* Wl    = (const float*)d_in[2];
    const float* bl    = (const float*)d_in[3];
    const float* Wr    = (const float*)d_in[4];
    const float* Wlo   = (const float*)d_in[5];
    const float* blo   = (const float*)d_in[6];
    const float* Wro   = (const float*)d_in[7];
    const float* gamma = (const float*)d_in[8];
    const float* beta  = (const float*)d_in[9];
    const float* alpha = (const float*)d_in[10];
    float* out = (float*)d_out;

    const int* esrc = ei;
    const int* edst = ei + NE;

    char* ws = (char*)d_ws;
    size_t off = 0;
    auto alloc = [&](size_t bytes) -> void* {
        void* p = ws + off;
        off += (bytes + 255) & ~(size_t)255;
        return p;
    };

    const int NB = (NN + 255) / 256;  // 391
    int*      counts  = (int*)alloc(NN * sizeof(int));
    int*      offsets = (int*)alloc((NN + 1) * sizeof(int));
    int*      bsums   = (int*)alloc(NB * sizeof(int));
    int*      rank    = (int*)alloc(NE * sizeof(int));
    int*      csr     = (int*)alloc(NE * sizeof(int));
    unsigned* mpk     = (unsigned*)alloc((size_t)NN * NF * 4);
    unsigned* hpk     = (unsigned*)alloc((size_t)NN * NF * 4);
    unsigned* zpk     = (unsigned*)alloc((size_t)NN * NF * 4);
    unsigned short* whi6 = (unsigned short*)alloc((size_t)6 * NF * 256 * 2);
    unsigned short* wlo6 = (unsigned short*)alloc((size_t)6 * NF * 256 * 2);
    float*    stats   = (float*)alloc(6 * 2 * NF * sizeof(float));

    hipMemsetAsync(counts, 0, NN * sizeof(int), stream);
    hipMemsetAsync(stats, 0, 6 * 2 * NF * sizeof(float), stream);

    // CSR build (atomic-free scatter via rank)
    k_hist<<<(NE + 255) / 256, 256, 0, stream>>>(edst, counts, rank);
    k_scan1<<<NB, 256, 0, stream>>>(counts, bsums);
    k_scan2<<<1, 512, 0, stream>>>(bsums, NB);
    k_scan3<<<NB, 256, 0, stream>>>(counts, bsums, offsets);
    k_scatter<<<(NE + 255) / 256, 256, 0, stream>>>(esrc, edst, offsets, rank, csr);

    // one-time packs/splits
    k_wsplit<<<(6 * NF * 256 + 255) / 256, 256, 0, stream>>>(Wl, Wr, whi6, wlo6);
    k_xpack<<<NN * NF / 4 / 256, 256, 0, stream>>>(x, hpk);

    const int aggGrid   = NN / 4;            // 25000
    const int gemmGridX = (NN + 255) / 256;  // 391
    const int normGrid  = NN * NF / 4 / 256; // 12500
    const int finGrid   = (NN + 63) / 64;

    for (int L = 0; L < 6; ++L) {
        k_aggmax<<<aggGrid, 256, 0, stream>>>(hpk, offsets, csr, mpk);
        k_gemm<<<dim3(gemmGridX, 2), 512, 0, stream>>>(mpk, hpk,
                                                       whi6 + (size_t)L * NF * 256,
                                                       wlo6 + (size_t)L * NF * 256,
                                                       bl + (size_t)L * NF,
                                                       zpk, stats + (size_t)L * 2 * NF);
        k_norm<<<normGrid, 256, 0, stream>>>(stats + (size_t)L * 2 * NF,
                                             gamma + (size_t)L * NF,
                                             beta + (size_t)L * NF,
                                             alpha + (size_t)L * NF,
                                             zpk, hpk);
    }
    // final layer
    k_aggmax<<<aggGrid, 256, 0, stream>>>(hpk, offsets, csr, mpk);
    k_final<<<finGrid, 256, 0, stream>>>(mpk, hpk, Wlo, blo, Wro, out);
}

// Round 11
// 1462.409 us; speedup vs baseline: 1.4652x; 1.0300x over previous
//
#include <hip/hip_runtime.h>
#include <math.h>

#define NN 100000
#define NE 1600000
#define NF 128
#define NOUT 3
#define NEGS 0.02f
#define GEPS 1e-5f

typedef __attribute__((ext_vector_type(8))) short bf16x8;
typedef __attribute__((ext_vector_type(4))) float f32x4;

__device__ __forceinline__ unsigned short bf16_rn(float f) {
    unsigned u = __float_as_uint(f);
    unsigned r = u + 0x7FFFu + ((u >> 16) & 1u);
    return (unsigned short)(r >> 16);
}
__device__ __forceinline__ float bf16_tf(unsigned short h) {
    return __uint_as_float((unsigned)h << 16);
}
// packed (hi,lo): value = tf(hi)+tf(lo), rel err ~2^-17
__device__ __forceinline__ unsigned pk2(float v) {
    unsigned short hi = bf16_rn(v);
    unsigned short lo = bf16_rn(v - bf16_tf(hi));
    return ((unsigned)hi << 16) | lo;
}
__device__ __forceinline__ float unpk(unsigned u) {
    return __uint_as_float(u & 0xFFFF0000u) + __uint_as_float(u << 16);
}

// ---------------- CSR build ----------------
__global__ void k_hist(const int* __restrict__ dst, int* __restrict__ counts,
                       int* __restrict__ rank) {
    int i = blockIdx.x * blockDim.x + threadIdx.x;
    if (i < NE) rank[i] = atomicAdd(&counts[dst[i]], 1);
}

__global__ void k_scan1(const int* __restrict__ counts, int* __restrict__ bsums) {
    __shared__ int s[256];
    int i = blockIdx.x * 256 + threadIdx.x;
    s[threadIdx.x] = (i < NN) ? counts[i] : 0;
    __syncthreads();
    for (int off = 128; off > 0; off >>= 1) {
        if (threadIdx.x < off) s[threadIdx.x] += s[threadIdx.x + off];
        __syncthreads();
    }
    if (threadIdx.x == 0) bsums[blockIdx.x] = s[0];
}

__global__ void k_scan2(int* __restrict__ bsums, int nb) {
    __shared__ int s[512];
    int t = threadIdx.x;
    int v = (t < nb) ? bsums[t] : 0;
    s[t] = v;
    __syncthreads();
    for (int off = 1; off < 512; off <<= 1) {
        int u = (t >= off) ? s[t - off] : 0;
        __syncthreads();
        s[t] += u;
        __syncthreads();
    }
    if (t < nb) bsums[t] = s[t] - v;   // exclusive
}

__global__ void k_scan3(const int* __restrict__ counts, const int* __restrict__ bsums,
                        int* __restrict__ offsets) {
    __shared__ int s[256];
    int i = blockIdx.x * 256 + threadIdx.x;
    int v = (i < NN) ? counts[i] : 0;
    s[threadIdx.x] = v;
    __syncthreads();
    for (int off = 1; off < 256; off <<= 1) {
        int u = (threadIdx.x >= off) ? s[threadIdx.x - off] : 0;
        __syncthreads();
        s[threadIdx.x] += u;
        __syncthreads();
    }
    int excl = s[threadIdx.x] - v + bsums[blockIdx.x];
    if (i <= NN) offsets[i] = excl;
}

__global__ void k_scatter(const int* __restrict__ src, const int* __restrict__ dst,
                          const int* __restrict__ offsets, const int* __restrict__ rank,
                          int* __restrict__ csr) {
    int i = blockIdx.x * blockDim.x + threadIdx.x;
    if (i < NE) csr[offsets[dst[i]] + rank[i]] = src[i];
}

// ---------------- weight split ----------------
__global__ void k_wsplit(const float* __restrict__ Wl, const float* __restrict__ Wr,
                         unsigned short* __restrict__ whi, unsigned short* __restrict__ wlo) {
    int i = blockIdx.x * 256 + threadIdx.x;
    if (i >= 6 * NF * 256) return;
    int L = i >> 15;
    int rem = i & 32767;
    int o = rem >> 8;
    int k = rem & 255;
    float v = (k < NF) ? Wl[L * NF * NF + o * NF + k] : Wr[L * NF * NF + o * NF + (k - NF)];
    unsigned short h = bf16_rn(v);
    whi[i] = h;
    wlo[i] = bf16_rn(v - bf16_tf(h));
}

// ---------------- x pack ----------------
__global__ void k_xpack(const float* __restrict__ x, unsigned* __restrict__ zpk) {
    int i = blockIdx.x * 256 + threadIdx.x;
    float4 v = ((const float4*)x)[i];
    uint4 p;
    p.x = pk2(v.x); p.y = pk2(v.y); p.z = pk2(v.z); p.w = pk2(v.w);
    ((uint4*)zpk)[i] = p;
}

// ---------------- scsh: identity (layer 0) and from-stats ----------------
__global__ void k_ident(float* __restrict__ scsh) {
    int f = threadIdx.x;           // 128
    scsh[f] = 1.0f;
    scsh[NF + f] = 0.0f;
}

__global__ void k_scsh(const float* __restrict__ stats, const float* __restrict__ gamma,
                       const float* __restrict__ beta, const float* __restrict__ alpha,
                       float* __restrict__ scsh) {
    int f = threadIdx.x;           // 128
    float mean = stats[f] * (1.0f / NN);
    float ex2 = stats[NF + f] * (1.0f / NN);
    float a = alpha[f];
    float am = a * mean;
    float var = ex2 - 2.f * am * mean + am * am;
    float inv = rsqrtf(var + GEPS);
    float g = gamma[f] * inv;      // NOTE: assumes g > 0 (gamma==1 in this problem)
    scsh[f] = g;
    scsh[NF + f] = beta[f] - g * am;
}

// ---------------- fused aggregation: max over raw z, then norm+leaky once per node ----------------
// valid because sc>0 and leaky are monotone: max(leaky(sc*z+sh)) = leaky(sc*max(z)+sh)
__global__ __launch_bounds__(256) void k_aggmax(const unsigned* __restrict__ zin,
                                                const int* __restrict__ offsets,
                                                const int* __restrict__ csr,
                                                const float* __restrict__ scsh,
                                                float neg,
                                                unsigned* __restrict__ mpk) {
    int node = blockIdx.x * 4 + (threadIdx.x >> 6);
    int l = threadIdx.x & 63;
    int beg = offsets[node], end = offsets[node + 1];
    float aa = -INFINITY, ab = -INFINITY;
    int e = beg;
    for (; e + 8 <= end; e += 8) {
        int s0 = csr[e],     s1 = csr[e + 1], s2 = csr[e + 2], s3 = csr[e + 3];
        int s4 = csr[e + 4], s5 = csr[e + 5], s6 = csr[e + 6], s7 = csr[e + 7];
        uint2 g0 = *(const uint2*)&zin[(size_t)s0 * NF + 2 * l];
        uint2 g1 = *(const uint2*)&zin[(size_t)s1 * NF + 2 * l];
        uint2 g2 = *(const uint2*)&zin[(size_t)s2 * NF + 2 * l];
        uint2 g3 = *(const uint2*)&zin[(size_t)s3 * NF + 2 * l];
        uint2 g4 = *(const uint2*)&zin[(size_t)s4 * NF + 2 * l];
        uint2 g5 = *(const uint2*)&zin[(size_t)s5 * NF + 2 * l];
        uint2 g6 = *(const uint2*)&zin[(size_t)s6 * NF + 2 * l];
        uint2 g7 = *(const uint2*)&zin[(size_t)s7 * NF + 2 * l];
        float m0 = fmaxf(fmaxf(unpk(g0.x), unpk(g1.x)), fmaxf(unpk(g2.x), unpk(g3.x)));
        float m1 = fmaxf(fmaxf(unpk(g4.x), unpk(g5.x)), fmaxf(unpk(g6.x), unpk(g7.x)));
        float n0 = fmaxf(fmaxf(unpk(g0.y), unpk(g1.y)), fmaxf(unpk(g2.y), unpk(g3.y)));
        float n1 = fmaxf(fmaxf(unpk(g4.y), unpk(g5.y)), fmaxf(unpk(g6.y), unpk(g7.y)));
        aa = fmaxf(aa, fmaxf(m0, m1));
        ab = fmaxf(ab, fmaxf(n0, n1));
    }
    for (; e < end; ++e) {
        uint2 g = *(const uint2*)&zin[(size_t)csr[e] * NF + 2 * l];
        aa = fmaxf(aa, unpk(g.x));
        ab = fmaxf(ab, unpk(g.y));
    }
    uint2 r;
    if (beg == end) {
        r.x = 0u; r.y = 0u;        // reference: empty segment -> 0 (pre-linear)
    } else {
        float sc0 = scsh[2 * l],      sc1 = scsh[2 * l + 1];
        float sh0 = scsh[NF + 2 * l], sh1 = scsh[NF + 2 * l + 1];
        float va = fmaf(sc0, aa, sh0); va = va > 0.f ? va : neg * va;
        float vb = fmaf(sc1, ab, sh1); vb = vb > 0.f ? vb : neg * vb;
        r.x = pk2(va); r.y = pk2(vb);
    }
    *(uint2*)&mpk[(size_t)node * NF + 2 * l] = r;
}

// ---------------- norm+leaky+split helper for GEMM self-path ----------------
__device__ __forceinline__ void norm_unpack(uint4 a, uint4 b, const float* sc, const float* sh,
                                            float neg, bf16x8* ah, bf16x8* al) {
    unsigned uu[8] = {a.x, a.y, a.z, a.w, b.x, b.y, b.z, b.w};
    unsigned hw[8], lw[8];
#pragma unroll
    for (int j = 0; j < 8; j++) {
        float v = fmaf(sc[j], unpk(uu[j]), sh[j]);
        v = v > 0.f ? v : neg * v;
        unsigned short h = bf16_rn(v);
        hw[j] = h;
        lw[j] = bf16_rn(v - bf16_tf(h));
    }
    union U { uint4 u; bf16x8 v; } H, L;
    H.u.x = hw[0] | (hw[1] << 16); H.u.y = hw[2] | (hw[3] << 16);
    H.u.z = hw[4] | (hw[5] << 16); H.u.w = hw[6] | (hw[7] << 16);
    L.u.x = lw[0] | (lw[1] << 16); L.u.y = lw[2] | (lw[3] << 16);
    L.u.z = lw[4] | (lw[5] << 16); L.u.w = lw[6] | (lw[7] << 16);
    *ah = H.v; *al = L.v;
}

// ---------------- MFMA GEMM, FULL 128-out row, weights resident in 128KB LDS ----------------
// grid 391, 512 thr = 8 waves; wave w: nodes tile*256 + w*32 (2x16), all 128 outs.
// Self-path h = leaky(sc*z+sh) computed on the fly. Fused per-feature stats.
__global__ __launch_bounds__(512) void k_gemm(const unsigned* __restrict__ zin,
                                              const unsigned* __restrict__ mpk,
                                              const unsigned short* __restrict__ whi,
                                              const unsigned short* __restrict__ wlo,
                                              const float* __restrict__ bias,
                                              const float* __restrict__ scsh,
                                              float neg,
                                              unsigned* __restrict__ zout,
                                              float* __restrict__ stats) {
    __shared__ __align__(16) unsigned short wlds[65536];   // 128KB
    __shared__ float slds[2 * NF];                          // sc | sh
    __shared__ float redS[NF], redQ[NF];
    const int tid = threadIdx.x;
    const int w = tid >> 6;
    const int l = tid & 63;
    const int arow = l & 15;
    const int kg = l >> 4;

    if (tid < NF) { redS[tid] = 0.f; redQ[tid] = 0.f; }
    if (tid >= 256 && tid < 512) slds[tid - 256] = scsh[tid - 256];

    // stage full weight block (hi 64KB + lo 64KB) into fragment order
#pragma unroll
    for (int i = 0; i < 16; i++) {
        int gd = tid + i * 512;            // 0..8191
        int arr = gd >> 12;                // 0=hi, 1=lo
        int rem = gd & 4095;
        int nt = rem >> 9;                 // 0..7
        int ks = (rem >> 6) & 7;
        int ls = rem & 63;
        int r = nt * 16 + (ls & 15);       // 0..127
        int g = ks * 4 + (ls >> 4);        // 0..31
        const unsigned short* srcw = arr ? wlo : whi;
        bf16x8 v = *(const bf16x8*)&srcw[(size_t)r * 256 + g * 8];
        *(bf16x8*)&wlds[arr * 32768 + rem * 8] = v;
    }
    __syncthreads();

    const int nbase = blockIdx.x * 256 + w * 32;
    int an0 = nbase + arow;      if (an0 > NN - 1) an0 = NN - 1;
    int an1 = nbase + 16 + arow; if (an1 > NN - 1) an1 = NN - 1;

    f32x4 acc0[8], acc1[8];
#pragma unroll
    for (int nt = 0; nt < 8; nt++) {
        acc0[nt] = (f32x4){0.f, 0.f, 0.f, 0.f};
        acc1[nt] = (f32x4){0.f, 0.f, 0.f, 0.f};
    }

    union U { uint4 u; bf16x8 v; };

#pragma unroll
    for (int ks = 0; ks < 8; ks++) {
        const int ak = (ks & 3) * 32 + kg * 8;
        bf16x8 ah0, al0, ah1, al1;
        if (ks < 4) {
            // m-path: already normed, pure bit-unpack
            uint4 p0 = *(const uint4*)&mpk[(size_t)an0 * NF + ak];
            uint4 p1 = *(const uint4*)&mpk[(size_t)an0 * NF + ak + 4];
            uint4 q0 = *(const uint4*)&mpk[(size_t)an1 * NF + ak];
            uint4 q1 = *(const uint4*)&mpk[(size_t)an1 * NF + ak + 4];
            U H0, L0, H1, L1;
            H0.u.x = (p0.x >> 16) | (p0.y & 0xFFFF0000u);
            H0.u.y = (p0.z >> 16) | (p0.w & 0xFFFF0000u);
            H0.u.z = (p1.x >> 16) | (p1.y & 0xFFFF0000u);
            H0.u.w = (p1.z >> 16) | (p1.w & 0xFFFF0000u);
            L0.u.x = (p0.x & 0xFFFFu) | (p0.y << 16);
            L0.u.y = (p0.z & 0xFFFFu) | (p0.w << 16);
            L0.u.z = (p1.x & 0xFFFFu) | (p1.y << 16);
            L0.u.w = (p1.z & 0xFFFFu) | (p1.w << 16);
            H1.u.x = (q0.x >> 16) | (q0.y & 0xFFFF0000u);
            H1.u.y = (q0.z >> 16) | (q0.w & 0xFFFF0000u);
            H1.u.z = (q1.x >> 16) | (q1.y & 0xFFFF0000u);
            H1.u.w = (q1.z >> 16) | (q1.w & 0xFFFF0000u);
            L1.u.x = (q0.x & 0xFFFFu) | (q0.y << 16);
            L1.u.y = (q0.z & 0xFFFFu) | (q0.w << 16);
            L1.u.z = (q1.x & 0xFFFFu) | (q1.y << 16);
            L1.u.w = (q1.z & 0xFFFFu) | (q1.w << 16);
            ah0 = H0.v; al0 = L0.v; ah1 = H1.v; al1 = L1.v;
        } else {
            // self-path: z -> norm+leaky on the fly
            uint4 p0 = *(const uint4*)&zin[(size_t)an0 * NF + ak];
            uint4 p1 = *(const uint4*)&zin[(size_t)an0 * NF + ak + 4];
            uint4 q0 = *(const uint4*)&zin[(size_t)an1 * NF + ak];
            uint4 q1 = *(const uint4*)&zin[(size_t)an1 * NF + ak + 4];
            float scv[8], shv[8];
#pragma unroll
            for (int j = 0; j < 8; j++) { scv[j] = slds[ak + j]; shv[j] = slds[NF + ak + j]; }
            norm_unpack(p0, p1, scv, shv, neg, &ah0, &al0);
            norm_unpack(q0, q1, scv, shv, neg, &ah1, &al1);
        }

#pragma unroll
        for (int nt = 0; nt < 8; nt++) {
            int el = (nt * 512 + ks * 64 + l) * 8;
            bf16x8 bh = *(const bf16x8*)&wlds[el];
            bf16x8 bl = *(const bf16x8*)&wlds[32768 + el];
            acc0[nt] = __builtin_amdgcn_mfma_f32_16x16x32_bf16(ah0, bh, acc0[nt], 0, 0, 0);
            acc1[nt] = __builtin_amdgcn_mfma_f32_16x16x32_bf16(ah1, bh, acc1[nt], 0, 0, 0);
            acc0[nt] = __builtin_amdgcn_mfma_f32_16x16x32_bf16(ah0, bl, acc0[nt], 0, 0, 0);
            acc1[nt] = __builtin_amdgcn_mfma_f32_16x16x32_bf16(ah1, bl, acc1[nt], 0, 0, 0);
            acc0[nt] = __builtin_amdgcn_mfma_f32_16x16x32_bf16(al0, bh, acc0[nt], 0, 0, 0);
            acc1[nt] = __builtin_amdgcn_mfma_f32_16x16x32_bf16(al1, bh, acc1[nt], 0, 0, 0);
        }
    }

    // epilogue: bias + packed store + fused stats
#pragma unroll
    for (int nt = 0; nt < 8; nt++) {
        const int f = nt * 16 + arow;
        const float b = bias[f];
        float s = 0.f, q = 0.f;
#pragma unroll
        for (int r = 0; r < 4; r++) {
            int n0 = nbase + kg * 4 + r;
            float v0 = acc0[nt][r] + b;
            if (n0 < NN) { zout[(size_t)n0 * NF + f] = pk2(v0); s += v0; q += v0 * v0; }
            int n1 = nbase + 16 + kg * 4 + r;
            float v1 = acc1[nt][r] + b;
            if (n1 < NN) { zout[(size_t)n1 * NF + f] = pk2(v1); s += v1; q += v1 * v1; }
        }
        s += __shfl_xor(s, 16); s += __shfl_xor(s, 32);
        q += __shfl_xor(q, 16); q += __shfl_xor(q, 32);
        if (l < 16) {
            atomicAdd(&redS[f], s);
            atomicAdd(&redQ[f], q);
        }
    }
    __syncthreads();
    if (tid < NF) {
        atomicAdd(&stats[tid], redS[tid]);
        atomicAdd(&stats[NF + tid], redQ[tid]);
    }
}

// ---------------- final layer: self-path normed on the fly ----------------
__global__ __launch_bounds__(256) void k_final(const unsigned* __restrict__ mpk,
                                               const unsigned* __restrict__ zin,
                                               const float* __restrict__ scsh,
                                               const float* __restrict__ Wlo_,
                                               const float* __restrict__ blo_,
                                               const float* __restrict__ Wro_,
                                               float* __restrict__ out) {
    __shared__ __align__(16) float W[NOUT][256];
    __shared__ float bb[NOUT];
    __shared__ float sss[2 * NF];
    int tid = threadIdx.x;
    for (int i = tid; i < NOUT * 256; i += 256) {
        int o = i >> 8, k = i & 255;
        W[o][k] = (k < NF) ? Wlo_[o * NF + k] : Wro_[o * NF + (k - NF)];
    }
    if (tid < 2 * NF) sss[tid] = scsh[tid];
    if (tid < NOUT) bb[tid] = blo_[tid];
    __syncthreads();

    int node = blockIdx.x * 64 + (tid >> 2);
    int j = tid & 3;
    if (node >= NN) return;
    const unsigned* sp = (j < 2) ? mpk : zin;
    int kbase = (j & 1) * 64;
    const unsigned* rp = &sp[(size_t)node * NF + kbase];
    float a0 = 0.f, a1 = 0.f, a2 = 0.f;
#pragma unroll
    for (int q = 0; q < 16; q++) {
        uint4 u = *(const uint4*)&rp[q * 4];
        float v0 = unpk(u.x), v1 = unpk(u.y), v2 = unpk(u.z), v3 = unpk(u.w);
        int k = j * 64 + q * 4;
        if (j >= 2) {   // self-path: apply norm + leaky
            int f = k - 128;
            float4 scv = *(const float4*)&sss[f];
            float4 shv = *(const float4*)&sss[NF + f];
            v0 = fmaf(scv.x, v0, shv.x); v0 = v0 > 0.f ? v0 : NEGS * v0;
            v1 = fmaf(scv.y, v1, shv.y); v1 = v1 > 0.f ? v1 : NEGS * v1;
            v2 = fmaf(scv.z, v2, shv.z); v2 = v2 > 0.f ? v2 : NEGS * v2;
            v3 = fmaf(scv.w, v3, shv.w); v3 = v3 > 0.f ? v3 : NEGS * v3;
        }
        float4 w0 = *(const float4*)&W[0][k];
        float4 w1 = *(const float4*)&W[1][k];
        float4 w2 = *(const float4*)&W[2][k];
        a0 += v0 * w0.x + v1 * w0.y + v2 * w0.z + v3 * w0.w;
        a1 += v0 * w1.x + v1 * w1.y + v2 * w1.z + v3 * w1.w;
        a2 += v0 * w2.x + v1 * w2.y + v2 * w2.z + v3 * w2.w;
    }
    a0 += __shfl_down(a0, 2, 4); a0 += __shfl_down(a0, 1, 4);
    a1 += __shfl_down(a1, 2, 4); a1 += __shfl_down(a1, 1, 4);
    a2 += __shfl_down(a2, 2, 4); a2 += __shfl_down(a2, 1, 4);
    if (j == 0) {
        out[node * 3 + 0] = tanhf(a0 + bb[0]) * 0.5f;
        out[node * 3 + 1] = tanhf(a1 + bb[1]) * 0.5f;
        out[node * 3 + 2] = tanhf(a2 + bb[2]) * 0.5f;
    }
}

extern "C" void kernel_launch(void* const* d_in, const int* in_sizes, int n_in,
                              void* d_out, int out_size, void* d_ws, size_t ws_size,
                              hipStream_t stream) {
    const float* x     = (const float*)d_in[0];
    const int*   ei    = (const int*)d_in[1];
    const float* Wl    = (const float*)d_in[2];
    const float* bl    = (const float*)d_in[3];
    const float* Wr    = (const float*)d_in[4];
    const float* Wlo   = (const float*)d_in[5];
    const float* blo   = (const float*)d_in[6];
    const float* Wro   = (const float*)d_in[7];
    const float* gamma = (const float*)d_in[8];
    const float* beta  = (const float*)d_in[9];
    const float* alpha = (const float*)d_in[10];
    float* out = (float*)d_out;

    const int* esrc = ei;
    const int* edst = ei + NE;

    char* ws = (char*)d_ws;
    size_t off = 0;
    auto alloc = [&](size_t bytes) -> void* {
        void* p = ws + off;
        off += (bytes + 255) & ~(size_t)255;
        return p;
    };

    const int NB = (NN + 255) / 256;  // 391
    int*      counts  = (int*)alloc(NN * sizeof(int));
    int*      offsets = (int*)alloc((NN + 1) * sizeof(int));
    int*      bsums   = (int*)alloc(NB * sizeof(int));
    int*      rank    = (int*)alloc(NE * sizeof(int));
    int*      csr     = (int*)alloc(NE * sizeof(int));
    unsigned* mpk     = (unsigned*)alloc((size_t)NN * NF * 4);
    unsigned* zA      = (unsigned*)alloc((size_t)NN * NF * 4);
    unsigned* zB      = (unsigned*)alloc((size_t)NN * NF * 4);
    unsigned short* whi6 = (unsigned short*)alloc((size_t)6 * NF * 256 * 2);
    unsigned short* wlo6 = (unsigned short*)alloc((size_t)6 * NF * 256 * 2);
    float*    stats   = (float*)alloc(6 * 2 * NF * sizeof(float));
    float*    scsh    = (float*)alloc(7 * 2 * NF * sizeof(float));

    hipMemsetAsync(counts, 0, NN * sizeof(int), stream);
    hipMemsetAsync(stats, 0, 6 * 2 * NF * sizeof(float), stream);

    // CSR build (atomic-free scatter via rank)
    k_hist<<<(NE + 255) / 256, 256, 0, stream>>>(edst, counts, rank);
    k_scan1<<<NB, 256, 0, stream>>>(counts, bsums);
    k_scan2<<<1, 512, 0, stream>>>(bsums, NB);
    k_scan3<<<NB, 256, 0, stream>>>(counts, bsums, offsets);
    k_scatter<<<(NE + 255) / 256, 256, 0, stream>>>(esrc, edst, offsets, rank, csr);

    // one-time packs/splits + identity transform for layer 0
    k_wsplit<<<(6 * NF * 256 + 255) / 256, 256, 0, stream>>>(Wl, Wr, whi6, wlo6);
    k_xpack<<<NN * NF / 4 / 256, 256, 0, stream>>>(x, zA);
    k_ident<<<1, 128, 0, stream>>>(scsh);

    const int aggGrid   = NN / 4;            // 25000
    const int gemmGridX = (NN + 255) / 256;  // 391
    const int finGrid   = (NN + 63) / 64;

    const unsigned* zin = zA;
    unsigned* zot = zB;
    for (int L = 0; L < 6; ++L) {
        float neg = (L == 0) ? 1.0f : NEGS;  // layer-0 input is raw x: identity, no leaky
        k_aggmax<<<aggGrid, 256, 0, stream>>>(zin, offsets, csr,
                                              scsh + (size_t)L * 2 * NF, neg, mpk);
        k_gemm<<<gemmGridX, 512, 0, stream>>>(zin, mpk,
                                              whi6 + (size_t)L * NF * 256,
                                              wlo6 + (size_t)L * NF * 256,
                                              bl + (size_t)L * NF,
                                              scsh + (size_t)L * 2 * NF, neg,
                                              zot, stats + (size_t)L * 2 * NF);
        k_scsh<<<1, 128, 0, stream>>>(stats + (size_t)L * 2 * NF,
                                      gamma + (size_t)L * NF,
                                      beta + (size_t)L * NF,
                                      alpha + (size_t)L * NF,
                                      scsh + (size_t)(L + 1) * 2 * NF);
        const unsigned* t = zin; zin = zot; zot = (unsigned*)t;
    }
    // final layer: aggregation + tiny GEMM, both apply scsh[6] on the fly
    k_aggmax<<<aggGrid, 256, 0, stream>>>(zin, offsets, csr,
                                          scsh + (size_t)6 * 2 * NF, NEGS, mpk);
    k_final<<<finGrid, 256, 0, stream>>>(mpk, zin, scsh + (size_t)6 * 2 * NF,
                                         Wlo, blo, Wro, out);
}